// Round 5
// baseline (637.020 us; speedup 1.0000x reference)
//
#include <hip/hip_runtime.h>
#include <hip/hip_fp16.h>
#include <math.h>

#define NN 51200
#define NE 2048000
#define F 128

typedef _Float16 half8 __attribute__((ext_vector_type(8)));
typedef float floatx4 __attribute__((ext_vector_type(4)));

__device__ __forceinline__ float mish_f(float x) {
  if (x > 20.0f) return x;
  float e = __expf(x);
  float w = 1.0f + e;
  w = w * w;
  return x * (w - 1.0f) / (w + 1.0f);
}

// ---- k_init: transpose W1,W2 to fp16 [128][K] AND zero cnt/degf/z -------
// 264 blocks x 256 = 67584 threads = 51200 (W1) + 16384 (W2) exactly.
// zero range: cnt|degf|z contiguous = 3*51200 floats.
__global__ __launch_bounds__(256) void k_init(const float* __restrict__ W1, const float* __restrict__ W2,
                                              _Float16* __restrict__ Wt1, _Float16* __restrict__ Wt2,
                                              float* __restrict__ zbase) {
  int idx = blockIdx.x * 256 + threadIdx.x;
  if (idx < 51200) {
    int k = idx >> 7, n = idx & 127;
    Wt1[n * 400 + k] = (_Float16)W1[idx];
  } else {
    int i2 = idx - 51200;
    int k = i2 >> 7, n = i2 & 127;
    Wt2[n * 128 + k] = (_Float16)W2[i2];
  }
  for (int i = idx; i < 3 * NN; i += 67584) zbase[i] = 0.0f;
}

// ---- k_cnt: per-edge global atomics -> degree count + weighted degree ----
__global__ __launch_bounds__(256) void k_cnt(const int* __restrict__ ei, const float* __restrict__ ew,
                                             int* __restrict__ cnt, float* __restrict__ degf) {
  int e = blockIdx.x * 256 + threadIdx.x;
  int dst = ei[NE + e];
  atomicAdd(&cnt[dst], 1);
  atomicAdd(&degf[dst], ew[e]);
}

// ---- hierarchical exclusive scan of cnt (NN elems) -> rowptr -------------
__global__ __launch_bounds__(256) void k_scan1(const int* __restrict__ cnt, int* __restrict__ bsum) {
  int i = blockIdx.x * 256 + threadIdx.x;
  int s = cnt[i];
#pragma unroll
  for (int off = 1; off < 64; off <<= 1) s += __shfl_xor(s, off);
  __shared__ int wsum[4];
  if ((threadIdx.x & 63) == 0) wsum[threadIdx.x >> 6] = s;
  __syncthreads();
  if (threadIdx.x == 0) bsum[blockIdx.x] = wsum[0] + wsum[1] + wsum[2] + wsum[3];
}

__global__ __launch_bounds__(256) void k_scan2(const int* __restrict__ bsum, int* __restrict__ boff,
                                               int* __restrict__ rowptr) {
  int t = threadIdx.x;
  int lane = t & 63, wid = t >> 6;
  int v = (t < 200) ? bsum[t] : 0;
  int x = v;
#pragma unroll
  for (int off = 1; off < 64; off <<= 1) {
    int y = __shfl_up(x, off);
    if (lane >= off) x += y;
  }
  __shared__ int ws4[4];
  if (lane == 63) ws4[wid] = x;
  __syncthreads();
  int woff = 0;
  for (int k = 0; k < wid; ++k) woff += ws4[k];
  if (t < 200) boff[t] = woff + x - v;
  if (t == 255) rowptr[NN] = woff + x;  // == NE
}

// scan3: rowptr[i] + mutable copy cur[i] + dinv[i]=rsqrt(degf[i]+1)
__global__ __launch_bounds__(256) void k_scan3(const int* __restrict__ cnt, const int* __restrict__ boff,
                                               const float* __restrict__ degf, int* __restrict__ rowptr,
                                               int* __restrict__ cur, float* __restrict__ dinv) {
  int i = blockIdx.x * 256 + threadIdx.x;
  int t = threadIdx.x;
  int lane = t & 63, wid = t >> 6;
  int v = cnt[i];
  int x = v;
#pragma unroll
  for (int off = 1; off < 64; off <<= 1) {
    int y = __shfl_up(x, off);
    if (lane >= off) x += y;
  }
  __shared__ int ws4[4];
  if (lane == 63) ws4[wid] = x;
  __syncthreads();
  int woff = boff[blockIdx.x];
  for (int k = 0; k < wid; ++k) woff += ws4[k];
  int rp = woff + x - v;
  rowptr[i] = rp;
  cur[i] = rp;
  dinv[i] = rsqrtf(degf[i] + 1.0f);  // +1 = self-loop weight
}

// ---- k_scat: place edges into CSR via atomic position-claim --------------
// csr entry packed 4B: src (16b, NN<65536) | fp16(dinv[src]*ew) << 16.
// Segment-internal order is irrelevant (sum is commutative).
__global__ __launch_bounds__(256) void k_scat(const int* __restrict__ ei, const float* __restrict__ ew,
                                              const float* __restrict__ dinv, int* __restrict__ cur,
                                              unsigned* __restrict__ csr) {
  int e = blockIdx.x * 256 + threadIdx.x;
  int dst = ei[NE + e];
  int src = ei[e];
  float w = dinv[src] * ew[e];
  int p = atomicAdd(&cur[dst], 1);
  unsigned pk = (unsigned)src | ((unsigned)__half_as_ushort(__float2half_rn(w)) << 16);
  __builtin_nontemporal_store(pk, &csr[p]);
}

// ---- MFMA GEMM: C[M,128](fp16, row-major) = A[M,K] @ W[K,128] ------------
template <bool A_IS_F32>
__global__ __launch_bounds__(256) void k_gemm16(const void* __restrict__ Av,
                                                const _Float16* __restrict__ Wt,
                                                __half* __restrict__ C, int K) {
  __shared__ _Float16 As[128][40];
  __shared__ _Float16 Bs[128][40];
  int t = threadIdx.x;
  int bm = blockIdx.x * 128;
  int w = t >> 6, l = t & 63, rr = l & 15, q = l >> 4;
  int si = t >> 1, sj = (t & 1) * 16;

  floatx4 acc[2][8];
#pragma unroll
  for (int a = 0; a < 2; ++a)
#pragma unroll
    for (int b = 0; b < 8; ++b) acc[a][b] = (floatx4){0.f, 0.f, 0.f, 0.f};

  for (int k0 = 0; k0 < K; k0 += 32) {
    if (A_IS_F32) {
      const float* A = (const float*)Av;
      half8 h0, h1;
      if (k0 + sj < K) {
        const float* ap = A + (size_t)(bm + si) * K + k0 + sj;
        float4 v0 = *(const float4*)(ap + 0);
        float4 v1 = *(const float4*)(ap + 4);
        float4 v2 = *(const float4*)(ap + 8);
        float4 v3 = *(const float4*)(ap + 12);
        h0 = (half8){(_Float16)v0.x, (_Float16)v0.y, (_Float16)v0.z, (_Float16)v0.w,
                     (_Float16)v1.x, (_Float16)v1.y, (_Float16)v1.z, (_Float16)v1.w};
        h1 = (half8){(_Float16)v2.x, (_Float16)v2.y, (_Float16)v2.z, (_Float16)v2.w,
                     (_Float16)v3.x, (_Float16)v3.y, (_Float16)v3.z, (_Float16)v3.w};
      } else {
        h0 = (half8){0, 0, 0, 0, 0, 0, 0, 0};
        h1 = h0;
      }
      *(half8*)&As[si][sj] = h0;
      *(half8*)&As[si][sj + 8] = h1;
    } else {
      const __half* A = (const __half*)Av;
      uint4 u0, u1;
      if (k0 + sj < K) {
        const __half* ap = A + (size_t)(bm + si) * K + k0 + sj;
        u0 = *(const uint4*)ap;
        u1 = *(const uint4*)(ap + 8);
      } else {
        u0 = make_uint4(0, 0, 0, 0);
        u1 = u0;
      }
      *(uint4*)&As[si][sj] = u0;
      *(uint4*)&As[si][sj + 8] = u1;
    }
    {
      uint4 u0, u1;
      if (k0 + sj < K) {
        const _Float16* wp = Wt + (size_t)si * K + k0 + sj;
        u0 = *(const uint4*)wp;
        u1 = *(const uint4*)(wp + 8);
      } else {
        u0 = make_uint4(0, 0, 0, 0);
        u1 = u0;
      }
      *(uint4*)&Bs[si][sj] = u0;
      *(uint4*)&Bs[si][sj + 8] = u1;
    }
    __syncthreads();

    half8 a0 = *(const half8*)&As[w * 32 + rr][q * 8];
    half8 a1 = *(const half8*)&As[w * 32 + 16 + rr][q * 8];
#pragma unroll
    for (int nt = 0; nt < 8; ++nt) {
      half8 b = *(const half8*)&Bs[nt * 16 + rr][q * 8];
      acc[0][nt] = __builtin_amdgcn_mfma_f32_16x16x32_f16(a0, b, acc[0][nt], 0, 0, 0);
      acc[1][nt] = __builtin_amdgcn_mfma_f32_16x16x32_f16(a1, b, acc[1][nt], 0, 0, 0);
    }
    __syncthreads();
  }
#pragma unroll
  for (int mt = 0; mt < 2; ++mt)
#pragma unroll
    for (int nt = 0; nt < 8; ++nt)
#pragma unroll
      for (int r4 = 0; r4 < 4; ++r4) {
        int row = bm + w * 32 + mt * 16 + q * 4 + r4;
        C[(size_t)row * 128 + nt * 16 + rr] = __float2half(acc[mt][nt][r4]);
      }
}

// ---- CSR aggregation + bias + mish: one node per WAVE (round-0 form) -----
// Wave-uniform csr loads via readfirstlane bounds; 16-deep batches for 16
// outstanding gathers; 4B packed csr entries (pre-scaled fp16 weight).
__global__ __launch_bounds__(256) void k_agg(const __half2* __restrict__ h, const int* __restrict__ rowptr,
                                             const unsigned* __restrict__ csr, const float* __restrict__ dinv,
                                             const float* __restrict__ bias, __half2* __restrict__ out) {
  unsigned lane = threadIdx.x & 63u;
  int n = blockIdx.x * 4 + (threadIdx.x >> 6);
  float di = dinv[n];
  float2 self = __half22float2(h[((unsigned)n << 6) + lane]);
  float sx = 0.f, sy = 0.f;
  int p = __builtin_amdgcn_readfirstlane(rowptr[n]);
  int p1 = __builtin_amdgcn_readfirstlane(rowptr[n + 1]);
  for (; p + 16 <= p1; p += 16) {
    unsigned c[16];
#pragma unroll
    for (int u = 0; u < 16; ++u) c[u] = csr[p + u];
    float2 f[16];
#pragma unroll
    for (int u = 0; u < 16; ++u) f[u] = __half22float2(h[((c[u] & 0xFFFFu) << 6) + lane]);
#pragma unroll
    for (int u = 0; u < 16; ++u) {
      float w = __half2float(__ushort_as_half((unsigned short)(c[u] >> 16)));
      sx += w * f[u].x;
      sy += w * f[u].y;
    }
  }
  for (; p + 4 <= p1; p += 4) {
    unsigned c[4];
#pragma unroll
    for (int u = 0; u < 4; ++u) c[u] = csr[p + u];
    float2 f[4];
#pragma unroll
    for (int u = 0; u < 4; ++u) f[u] = __half22float2(h[((c[u] & 0xFFFFu) << 6) + lane]);
#pragma unroll
    for (int u = 0; u < 4; ++u) {
      float w = __half2float(__ushort_as_half((unsigned short)(c[u] >> 16)));
      sx += w * f[u].x;
      sy += w * f[u].y;
    }
  }
  for (; p < p1; ++p) {
    unsigned c0 = csr[p];
    float2 f0 = __half22float2(h[((c0 & 0xFFFFu) << 6) + lane]);
    float w = __half2float(__ushort_as_half((unsigned short)(c0 >> 16)));
    sx += w * f0.x;
    sy += w * f0.y;
  }
  float ax = di * (di * self.x + sx);
  float ay = di * (di * self.y + sy);
  float2 bb = ((const float2*)bias)[lane];
  out[((unsigned)n << 6) + lane] = __floats2half2_rn(mish_f(ax + bb.x), mish_f(ay + bb.y));
}

// ---- readout (fp16 h): o8[n,k] = mish(h[n,:]@ro_w[:,k] + ro_b[k]) --------
__global__ __launch_bounds__(256) void k_ro(const __half2* __restrict__ h, const float* __restrict__ rw,
                                            const float* __restrict__ rb, float* __restrict__ o8) {
  __shared__ float w[128 * 8];
  int t = threadIdx.x;
  for (int i = t; i < 1024; i += 256) w[i] = rw[i];
  __syncthreads();
  int n = blockIdx.x * 32 + (t >> 3);
  int k = t & 7;
  const __half2* hr = h + (size_t)n * 64;
  float acc = rb[k];
#pragma unroll 4
  for (int j = 0; j < 64; ++j) {
    float2 hv = __half22float2(hr[j]);
    acc += hv.x * w[(2 * j) * 8 + k] + hv.y * w[(2 * j + 1) * 8 + k];
  }
  o8[(size_t)n * 8 + k] = mish_f(acc);
}

// ---- fc1 split-K: z += feats[g, kc:kc+128] @ w[kc:kc+128, :] -------------
// NOTE: fc1 bias intentionally omitted -- BatchNorm (training mode) is
// exactly invariant to a per-feature constant added to z (it shifts mu).
__global__ __launch_bounds__(448) void k_fc1(const float* __restrict__ feats, const float* __restrict__ w,
                                             float* __restrict__ z) {
  __shared__ float fs[8][128];
  int t = threadIdx.x;
  int kc = blockIdx.x * 128;
  int g0 = blockIdx.y * 8;
  for (int i = t; i < 1024; i += 448) {
    int g = i >> 7, k = i & 127;
    fs[g][k] = feats[(size_t)(g0 + g) * 3200 + kc + k];
  }
  __syncthreads();
  if (t < 400) {
    float a[8];
#pragma unroll
    for (int g = 0; g < 8; ++g) a[g] = 0.0f;
    for (int k = 0; k < 128; ++k) {
      float wv = w[(size_t)(kc + k) * 400 + t];
#pragma unroll
      for (int g = 0; g < 8; ++g) a[g] += fs[g][k] * wv;
    }
#pragma unroll
    for (int g = 0; g < 8; ++g) atomicAdd(&z[(size_t)(g0 + g) * 400 + t], a[g]);
  }
}

// ---- batchnorm stats: one block per feature, thread = batch element ------
__global__ __launch_bounds__(128) void k_bn(const float* __restrict__ z, const float* __restrict__ gamma,
                                            const float* __restrict__ beta, float* __restrict__ gs,
                                            float* __restrict__ gb) {
  int j = blockIdx.x;
  int b = threadIdx.x;
  float v = z[b * 400 + j];
  float s = v, s2 = v * v;
#pragma unroll
  for (int off = 1; off < 64; off <<= 1) {
    s += __shfl_xor(s, off);
    s2 += __shfl_xor(s2, off);
  }
  __shared__ float ls[2], ls2[2];
  if ((b & 63) == 0) {
    ls[b >> 6] = s;
    ls2[b >> 6] = s2;
  }
  __syncthreads();
  if (b == 0) {
    float mu = (ls[0] + ls[1]) * (1.0f / 128.0f);
    float var = (ls2[0] + ls2[1]) * (1.0f / 128.0f) - mu * mu;
    float rs = rsqrtf(var + 1e-5f);
    float g = gamma[j] * rs;
    gs[j] = g;
    gb[j] = beta[j] - mu * g;
  }
}

// ---- fc2: one block per graph, block-reduce over j -----------------------
__global__ __launch_bounds__(256) void k_fc2(const float* __restrict__ z, const float* __restrict__ gs,
                                             const float* __restrict__ gb, const float* __restrict__ w2,
                                             const float* __restrict__ b2, float* __restrict__ out) {
  int bg = blockIdx.x;
  int t = threadIdx.x;
  float a0 = 0.f, a1 = 0.f;
  for (int j = t; j < 400; j += 256) {
    float zn = z[bg * 400 + j] * gs[j] + gb[j];
    float m = mish_f(zn);
    a0 += m * w2[j * 2];
    a1 += m * w2[j * 2 + 1];
  }
#pragma unroll
  for (int off = 1; off < 64; off <<= 1) {
    a0 += __shfl_xor(a0, off);
    a1 += __shfl_xor(a1, off);
  }
  __shared__ float s0[4], s1[4];
  if ((t & 63) == 0) {
    s0[t >> 6] = a0;
    s1[t >> 6] = a1;
  }
  __syncthreads();
  if (t == 0) {
    out[bg * 2 + 0] = b2[0] + s0[0] + s0[1] + s0[2] + s0[3];
    out[bg * 2 + 1] = b2[1] + s1[0] + s1[1] + s1[2] + s1[3];
  }
}

extern "C" void kernel_launch(void* const* d_in, const int* in_sizes, int n_in,
                              void* d_out, int out_size, void* d_ws, size_t ws_size,
                              hipStream_t stream) {
  (void)in_sizes; (void)n_in; (void)out_size; (void)ws_size;
  const float* x   = (const float*)d_in[0];
  const int*   ei  = (const int*)d_in[1];
  const float* ew  = (const float*)d_in[2];
  const float* c1w = (const float*)d_in[4];
  const float* c1b = (const float*)d_in[5];
  const float* c2w = (const float*)d_in[6];
  const float* c2b = (const float*)d_in[7];
  const float* rw  = (const float*)d_in[8];
  const float* rb  = (const float*)d_in[9];
  const float* f1w = (const float*)d_in[10];
  const float* bng = (const float*)d_in[12];
  const float* bnb = (const float*)d_in[13];
  const float* f2w = (const float*)d_in[14];
  const float* f2b = (const float*)d_in[15];
  float* out = (float*)d_out;

  char* ws = (char*)d_ws;
  size_t off = 0;
  auto alloc = [&](size_t bytes) {
    void* p = ws + off;
    off = (off + bytes + 255) & ~(size_t)255;
    return p;
  };
  // cnt | degf | z contiguous (each 51200*4 B, multiple of 256) -> one
  // zero-fill range in k_init.
  int*   cnt     = (int*)alloc((size_t)NN * 4);
  float* degf    = (float*)alloc((size_t)NN * 4);
  float* z       = (float*)alloc((size_t)NN * 4);  // 128*400 == NN floats
  float* dinv    = (float*)alloc((size_t)NN * 4);
  int*   rowptr  = (int*)alloc((size_t)(NN + 1) * 4);
  int*   cur     = (int*)alloc((size_t)NN * 4);
  int*   bsum    = (int*)alloc(200 * 4);
  int*   boff    = (int*)alloc(200 * 4);
  unsigned* csr  = (unsigned*)alloc((size_t)NE * 4 + 64);    // 8.2 MB packed
  __half* A1     = (__half*)alloc((size_t)NN * F * 2);       // gemm out (fp16)
  __half* B1     = (__half*)alloc((size_t)NN * F * 2);       // agg out (fp16)
  _Float16* Wt1  = (_Float16*)alloc((size_t)400 * 128 * 2);
  _Float16* Wt2  = (_Float16*)alloc((size_t)128 * 128 * 2);
  float* o8      = (float*)alloc((size_t)NN * 8 * 4);
  float* gs      = (float*)alloc(400 * 4);
  float* gb      = (float*)alloc(400 * 4);

  // 14 dispatches total (was 20).
  k_init<<<264, 256, 0, stream>>>(c1w, c2w, Wt1, Wt2, (float*)cnt);
  k_cnt<<<NE / 256, 256, 0, stream>>>(ei, ew, cnt, degf);
  k_scan1<<<NN / 256, 256, 0, stream>>>(cnt, bsum);
  k_scan2<<<1, 256, 0, stream>>>(bsum, boff, rowptr);
  k_scan3<<<NN / 256, 256, 0, stream>>>(cnt, boff, degf, rowptr, cur, dinv);
  k_scat<<<NE / 256, 256, 0, stream>>>(ei, ew, dinv, cur, csr);

  // conv1: h = x@W1 (MFMA, fp16 out) ; agg+bias+mish (fp16 out)
  k_gemm16<true><<<NN / 128, 256, 0, stream>>>(x, Wt1, A1, 400);
  k_agg<<<NN / 4, 256, 0, stream>>>((const __half2*)A1, rowptr, csr, dinv, c1b, (__half2*)B1);
  // conv2
  k_gemm16<false><<<NN / 128, 256, 0, stream>>>(B1, Wt2, A1, 128);
  k_agg<<<NN / 4, 256, 0, stream>>>((const __half2*)A1, rowptr, csr, dinv, c2b, (__half2*)B1);
  // readout -> feats (o8 flat IS feats[128][3200])
  k_ro<<<NN / 32, 256, 0, stream>>>((const __half2*)B1, rw, rb, o8);
  {
    dim3 g(25, 16);
    k_fc1<<<g, 448, 0, stream>>>(o8, f1w, z);
  }
  k_bn<<<400, 128, 0, stream>>>(z, bng, bnb, gs, gb);
  k_fc2<<<128, 256, 0, stream>>>(z, gs, gb, f2w, f2b, out);
}

// Round 6
// 472.793 us; speedup vs baseline: 1.3474x; 1.3474x over previous
//
#include <hip/hip_runtime.h>
#include <hip/hip_fp16.h>
#include <math.h>

#define NN 51200
#define NE 2048000
#define F 128
#define NB 1000        // coarse blocks
#define EPB 2048       // edges per coarse block (NB*EPB == NE)
#define NBKT 200       // coarse buckets (dst >> 8)

typedef _Float16 half8 __attribute__((ext_vector_type(8)));
typedef float floatx4 __attribute__((ext_vector_type(4)));

__device__ __forceinline__ float mish_f(float x) {
  if (x > 20.0f) return x;
  float e = __expf(x);
  float w = 1.0f + e;
  w = w * w;
  return x * (w - 1.0f) / (w + 1.0f);
}

// ---- k_init: transpose W1,W2 to fp16 [128][K] AND zero z -----------------
// 264 blocks x 256 = 67584 threads = 51200 (W1) + 16384 (W2) exactly.
__global__ __launch_bounds__(256) void k_init(const float* __restrict__ W1, const float* __restrict__ W2,
                                              _Float16* __restrict__ Wt1, _Float16* __restrict__ Wt2,
                                              float* __restrict__ z) {
  int idx = blockIdx.x * 256 + threadIdx.x;
  if (idx < 51200) {
    int k = idx >> 7, n = idx & 127;
    Wt1[n * 400 + k] = (_Float16)W1[idx];
    z[idx] = 0.0f;  // z is 128*400 == 51200 floats
  } else {
    int i2 = idx - 51200;
    int k = i2 >> 7, n = i2 & 127;
    Wt2[n * 128 + k] = (_Float16)W2[i2];
  }
}

// ---- pass A: coarse LDS histogram over dst>>8 ----------------------------
__global__ __launch_bounds__(256) void k_chist(const int* __restrict__ ei, unsigned* __restrict__ G) {
  __shared__ unsigned hist[NBKT];
  int blk = blockIdx.x, t = threadIdx.x;
  for (int i = t; i < NBKT; i += 256) hist[i] = 0u;
  __syncthreads();
  int base = blk * EPB;
  for (int it = 0; it < EPB; it += 256) {
    int dst = ei[NE + base + it + t];
    atomicAdd(&hist[dst >> 8], 1u);
  }
  __syncthreads();
  for (int i = t; i < NBKT; i += 256) G[(size_t)i * NB + blk] = hist[i];
}

// ---- pass B: per-bucket exclusive scan over the NB blocks (1 wave/bucket)
__global__ __launch_bounds__(64) void k_bscan(unsigned* __restrict__ G, unsigned* __restrict__ btot) {
  int b = blockIdx.x, l = threadIdx.x;
  unsigned base = (unsigned)l * 16;
  unsigned loc[16];
  unsigned s = 0;
#pragma unroll
  for (int i = 0; i < 16; ++i) {
    unsigned idx = base + i;
    unsigned x = (idx < NB) ? G[(size_t)b * NB + idx] : 0u;
    loc[i] = s;
    s += x;
  }
  unsigned run = s;
#pragma unroll
  for (int off = 1; off < 64; off <<= 1) {
    unsigned y = __shfl_up(run, off);
    if (l >= off) run += y;
  }
  unsigned excl = run - s;
#pragma unroll
  for (int i = 0; i < 16; ++i) {
    unsigned idx = base + i;
    if (idx < NB) G[(size_t)b * NB + idx] = excl + loc[i];
  }
  if (l == 63) btot[b] = run;
}

// ---- scan 200 bucket totals -> bbase[0..200] -----------------------------
__global__ __launch_bounds__(256) void k_bbase(const unsigned* __restrict__ btot, unsigned* __restrict__ bbase) {
  int t = threadIdx.x, lane = t & 63, wid = t >> 6;
  unsigned v = (t < NBKT) ? btot[t] : 0u;
  unsigned x = v;
#pragma unroll
  for (int off = 1; off < 64; off <<= 1) {
    unsigned y = __shfl_up(x, off);
    if (lane >= off) x += y;
  }
  __shared__ unsigned ws4[4];
  if (lane == 63) ws4[wid] = x;
  __syncthreads();
  unsigned woff = 0;
  for (int k = 0; k < wid; ++k) woff += ws4[k];
  if (t < NBKT) bbase[t] = woff + x - v;
  if (t == 255) bbase[NBKT] = woff + x;  // == NE
}

// ---- pass C: scatter edges into bucket-grouped E (packed src|dstLow, ew) -
__global__ __launch_bounds__(256) void k_cscat(const int* __restrict__ ei, const float* __restrict__ ew,
                                               const unsigned* __restrict__ G,
                                               const unsigned* __restrict__ bbase,
                                               uint2* __restrict__ E) {
  __shared__ unsigned cur[NBKT];
  int blk = blockIdx.x, t = threadIdx.x;
  for (int i = t; i < NBKT; i += 256) cur[i] = bbase[i] + G[(size_t)i * NB + blk];
  __syncthreads();
  int base = blk * EPB;
  for (int it = 0; it < EPB; it += 256) {
    int e = base + it + t;
    int dst = ei[NE + e];
    int src = ei[e];
    float w = ew[e];
    unsigned pos = atomicAdd(&cur[dst >> 8], 1u);
    E[pos] = make_uint2((unsigned)src | ((unsigned)(dst & 255) << 16), __float_as_uint(w));
  }
}

// ---- pass D1: per-bucket fine count + degree sum -> cnt, dinv ------------
__global__ __launch_bounds__(256) void k_fcnt(const uint2* __restrict__ E, const unsigned* __restrict__ bbase,
                                              int* __restrict__ cnt, float* __restrict__ dinv) {
  __shared__ unsigned lc[256];
  __shared__ float ld[256];
  int b = blockIdx.x, t = threadIdx.x;
  lc[t] = 0u;
  ld[t] = 0.f;
  __syncthreads();
  unsigned e0 = bbase[b], e1 = bbase[b + 1];
  for (unsigned e = e0 + t; e < e1; e += 256) {
    uint2 v = E[e];
    unsigned node = (v.x >> 16) & 255u;
    atomicAdd(&lc[node], 1u);
    atomicAdd(&ld[node], __uint_as_float(v.y));
  }
  __syncthreads();
  cnt[b * 256 + t] = (int)lc[t];
  dinv[b * 256 + t] = rsqrtf(ld[t] + 1.0f);  // +1 = self-loop weight
}

// ---- hierarchical exclusive scan of cnt -> rowptr ------------------------
__global__ __launch_bounds__(256) void k_scan1(const int* __restrict__ cnt, int* __restrict__ bsum) {
  int i = blockIdx.x * 256 + threadIdx.x;
  int s = cnt[i];
#pragma unroll
  for (int off = 1; off < 64; off <<= 1) s += __shfl_xor(s, off);
  __shared__ int wsum[4];
  if ((threadIdx.x & 63) == 0) wsum[threadIdx.x >> 6] = s;
  __syncthreads();
  if (threadIdx.x == 0) bsum[blockIdx.x] = wsum[0] + wsum[1] + wsum[2] + wsum[3];
}

__global__ __launch_bounds__(256) void k_scan2(const int* __restrict__ bsum, int* __restrict__ boff,
                                               int* __restrict__ rowptr) {
  int t = threadIdx.x;
  int lane = t & 63, wid = t >> 6;
  int v = (t < 200) ? bsum[t] : 0;
  int x = v;
#pragma unroll
  for (int off = 1; off < 64; off <<= 1) {
    int y = __shfl_up(x, off);
    if (lane >= off) x += y;
  }
  __shared__ int ws4[4];
  if (lane == 63) ws4[wid] = x;
  __syncthreads();
  int woff = 0;
  for (int k = 0; k < wid; ++k) woff += ws4[k];
  if (t < 200) boff[t] = woff + x - v;
  if (t == 255) rowptr[NN] = woff + x;  // grand total
}

__global__ __launch_bounds__(256) void k_scan3(const int* __restrict__ cnt, const int* __restrict__ boff,
                                               int* __restrict__ rowptr) {
  int i = blockIdx.x * 256 + threadIdx.x;
  int t = threadIdx.x;
  int lane = t & 63, wid = t >> 6;
  int v = cnt[i];
  int x = v;
#pragma unroll
  for (int off = 1; off < 64; off <<= 1) {
    int y = __shfl_up(x, off);
    if (lane >= off) x += y;
  }
  __shared__ int ws4[4];
  if (lane == 63) ws4[wid] = x;
  __syncthreads();
  int woff = boff[blockIdx.x];
  for (int k = 0; k < wid; ++k) woff += ws4[k];
  rowptr[i] = woff + x - v;
}

// ---- pass D2: per-bucket scatter into final CSR --------------------------
// csr entry packed 4B: src (16b, NN<65536) | fp16(dinv[src]*ew) << 16.
// fp16 weight rel-err ~5e-4 (validated: absmax 0.0039 across rounds 1-5).
__global__ __launch_bounds__(256) void k_fscat(const uint2* __restrict__ E, const unsigned* __restrict__ bbase,
                                               const int* __restrict__ rowptr, const float* __restrict__ dinv,
                                               unsigned* __restrict__ csr) {
  __shared__ int cur[256];
  int b = blockIdx.x, t = threadIdx.x;
  cur[t] = rowptr[b * 256 + t];
  __syncthreads();
  unsigned e0 = bbase[b], e1 = bbase[b + 1];
  for (unsigned e = e0 + t; e < e1; e += 256) {
    uint2 v = E[e];
    unsigned node = (v.x >> 16) & 255u;
    unsigned src = v.x & 0xFFFFu;
    float w = dinv[src] * __uint_as_float(v.y);
    int p = atomicAdd(&cur[node], 1);
    unsigned pk = src | ((unsigned)__half_as_ushort(__float2half_rn(w)) << 16);
    __builtin_nontemporal_store(pk, &csr[p]);
  }
}

// ---- MFMA GEMM: C[M,128](fp16, row-major) = A[M,K] @ W[K,128] ------------
template <bool A_IS_F32>
__global__ __launch_bounds__(256) void k_gemm16(const void* __restrict__ Av,
                                                const _Float16* __restrict__ Wt,
                                                __half* __restrict__ C, int K) {
  __shared__ _Float16 As[128][40];
  __shared__ _Float16 Bs[128][40];
  int t = threadIdx.x;
  int bm = blockIdx.x * 128;
  int w = t >> 6, l = t & 63, rr = l & 15, q = l >> 4;
  int si = t >> 1, sj = (t & 1) * 16;

  floatx4 acc[2][8];
#pragma unroll
  for (int a = 0; a < 2; ++a)
#pragma unroll
    for (int b = 0; b < 8; ++b) acc[a][b] = (floatx4){0.f, 0.f, 0.f, 0.f};

  for (int k0 = 0; k0 < K; k0 += 32) {
    if (A_IS_F32) {
      const float* A = (const float*)Av;
      half8 h0, h1;
      if (k0 + sj < K) {
        const float* ap = A + (size_t)(bm + si) * K + k0 + sj;
        float4 v0 = *(const float4*)(ap + 0);
        float4 v1 = *(const float4*)(ap + 4);
        float4 v2 = *(const float4*)(ap + 8);
        float4 v3 = *(const float4*)(ap + 12);
        h0 = (half8){(_Float16)v0.x, (_Float16)v0.y, (_Float16)v0.z, (_Float16)v0.w,
                     (_Float16)v1.x, (_Float16)v1.y, (_Float16)v1.z, (_Float16)v1.w};
        h1 = (half8){(_Float16)v2.x, (_Float16)v2.y, (_Float16)v2.z, (_Float16)v2.w,
                     (_Float16)v3.x, (_Float16)v3.y, (_Float16)v3.z, (_Float16)v3.w};
      } else {
        h0 = (half8){0, 0, 0, 0, 0, 0, 0, 0};
        h1 = h0;
      }
      *(half8*)&As[si][sj] = h0;
      *(half8*)&As[si][sj + 8] = h1;
    } else {
      const __half* A = (const __half*)Av;
      uint4 u0, u1;
      if (k0 + sj < K) {
        const __half* ap = A + (size_t)(bm + si) * K + k0 + sj;
        u0 = *(const uint4*)ap;
        u1 = *(const uint4*)(ap + 8);
      } else {
        u0 = make_uint4(0, 0, 0, 0);
        u1 = u0;
      }
      *(uint4*)&As[si][sj] = u0;
      *(uint4*)&As[si][sj + 8] = u1;
    }
    {
      uint4 u0, u1;
      if (k0 + sj < K) {
        const _Float16* wp = Wt + (size_t)si * K + k0 + sj;
        u0 = *(const uint4*)wp;
        u1 = *(const uint4*)(wp + 8);
      } else {
        u0 = make_uint4(0, 0, 0, 0);
        u1 = u0;
      }
      *(uint4*)&Bs[si][sj] = u0;
      *(uint4*)&Bs[si][sj + 8] = u1;
    }
    __syncthreads();

    half8 a0 = *(const half8*)&As[w * 32 + rr][q * 8];
    half8 a1 = *(const half8*)&As[w * 32 + 16 + rr][q * 8];
#pragma unroll
    for (int nt = 0; nt < 8; ++nt) {
      half8 b = *(const half8*)&Bs[nt * 16 + rr][q * 8];
      acc[0][nt] = __builtin_amdgcn_mfma_f32_16x16x32_f16(a0, b, acc[0][nt], 0, 0, 0);
      acc[1][nt] = __builtin_amdgcn_mfma_f32_16x16x32_f16(a1, b, acc[1][nt], 0, 0, 0);
    }
    __syncthreads();
  }
#pragma unroll
  for (int mt = 0; mt < 2; ++mt)
#pragma unroll
    for (int nt = 0; nt < 8; ++nt)
#pragma unroll
      for (int r4 = 0; r4 < 4; ++r4) {
        int row = bm + w * 32 + mt * 16 + q * 4 + r4;
        C[(size_t)row * 128 + nt * 16 + rr] = __float2half(acc[mt][nt][r4]);
      }
}

// ---- CSR aggregation + bias + mish: one node per WAVE --------------------
// Wave-uniform csr loads via readfirstlane bounds; 16-deep batches for 16
// outstanding gathers; 4B packed csr entries (pre-scaled fp16 weight).
__global__ __launch_bounds__(256) void k_agg(const __half2* __restrict__ h, const int* __restrict__ rowptr,
                                             const unsigned* __restrict__ csr, const float* __restrict__ dinv,
                                             const float* __restrict__ bias, __half2* __restrict__ out) {
  unsigned lane = threadIdx.x & 63u;
  int n = blockIdx.x * 4 + (threadIdx.x >> 6);
  float di = dinv[n];
  float2 self = __half22float2(h[((unsigned)n << 6) + lane]);
  float sx = 0.f, sy = 0.f;
  int p = __builtin_amdgcn_readfirstlane(rowptr[n]);
  int p1 = __builtin_amdgcn_readfirstlane(rowptr[n + 1]);
  for (; p + 16 <= p1; p += 16) {
    unsigned c[16];
#pragma unroll
    for (int u = 0; u < 16; ++u) c[u] = csr[p + u];
    float2 f[16];
#pragma unroll
    for (int u = 0; u < 16; ++u) f[u] = __half22float2(h[((c[u] & 0xFFFFu) << 6) + lane]);
#pragma unroll
    for (int u = 0; u < 16; ++u) {
      float w = __half2float(__ushort_as_half((unsigned short)(c[u] >> 16)));
      sx += w * f[u].x;
      sy += w * f[u].y;
    }
  }
  for (; p + 4 <= p1; p += 4) {
    unsigned c[4];
#pragma unroll
    for (int u = 0; u < 4; ++u) c[u] = csr[p + u];
    float2 f[4];
#pragma unroll
    for (int u = 0; u < 4; ++u) f[u] = __half22float2(h[((c[u] & 0xFFFFu) << 6) + lane]);
#pragma unroll
    for (int u = 0; u < 4; ++u) {
      float w = __half2float(__ushort_as_half((unsigned short)(c[u] >> 16)));
      sx += w * f[u].x;
      sy += w * f[u].y;
    }
  }
  for (; p < p1; ++p) {
    unsigned c0 = csr[p];
    float2 f0 = __half22float2(h[((c0 & 0xFFFFu) << 6) + lane]);
    float w = __half2float(__ushort_as_half((unsigned short)(c0 >> 16)));
    sx += w * f0.x;
    sy += w * f0.y;
  }
  float ax = di * (di * self.x + sx);
  float ay = di * (di * self.y + sy);
  float2 bb = ((const float2*)bias)[lane];
  out[((unsigned)n << 6) + lane] = __floats2half2_rn(mish_f(ax + bb.x), mish_f(ay + bb.y));
}

// ---- readout (fp16 h): o8[n,k] = mish(h[n,:]@ro_w[:,k] + ro_b[k]) --------
__global__ __launch_bounds__(256) void k_ro(const __half2* __restrict__ h, const float* __restrict__ rw,
                                            const float* __restrict__ rb, float* __restrict__ o8) {
  __shared__ float w[128 * 8];
  int t = threadIdx.x;
  for (int i = t; i < 1024; i += 256) w[i] = rw[i];
  __syncthreads();
  int n = blockIdx.x * 32 + (t >> 3);
  int k = t & 7;
  const __half2* hr = h + (size_t)n * 64;
  float acc = rb[k];
#pragma unroll 4
  for (int j = 0; j < 64; ++j) {
    float2 hv = __half22float2(hr[j]);
    acc += hv.x * w[(2 * j) * 8 + k] + hv.y * w[(2 * j + 1) * 8 + k];
  }
  o8[(size_t)n * 8 + k] = mish_f(acc);
}

// ---- fc1 split-K: z += feats[g, kc:kc+128] @ w[kc:kc+128, :] -------------
// fc1 bias intentionally omitted: BatchNorm (training mode) is exactly
// invariant to a per-feature constant added to z (it shifts mu equally).
__global__ __launch_bounds__(448) void k_fc1(const float* __restrict__ feats, const float* __restrict__ w,
                                             float* __restrict__ z) {
  __shared__ float fs[8][128];
  int t = threadIdx.x;
  int kc = blockIdx.x * 128;
  int g0 = blockIdx.y * 8;
  for (int i = t; i < 1024; i += 448) {
    int g = i >> 7, k = i & 127;
    fs[g][k] = feats[(size_t)(g0 + g) * 3200 + kc + k];
  }
  __syncthreads();
  if (t < 400) {
    float a[8];
#pragma unroll
    for (int g = 0; g < 8; ++g) a[g] = 0.0f;
    for (int k = 0; k < 128; ++k) {
      float wv = w[(size_t)(kc + k) * 400 + t];
#pragma unroll
      for (int g = 0; g < 8; ++g) a[g] += fs[g][k] * wv;
    }
#pragma unroll
    for (int g = 0; g < 8; ++g) atomicAdd(&z[(size_t)(g0 + g) * 400 + t], a[g]);
  }
}

// ---- batchnorm stats: one block per feature, thread = batch element ------
__global__ __launch_bounds__(128) void k_bn(const float* __restrict__ z, const float* __restrict__ gamma,
                                            const float* __restrict__ beta, float* __restrict__ gs,
                                            float* __restrict__ gb) {
  int j = blockIdx.x;
  int b = threadIdx.x;
  float v = z[b * 400 + j];
  float s = v, s2 = v * v;
#pragma unroll
  for (int off = 1; off < 64; off <<= 1) {
    s += __shfl_xor(s, off);
    s2 += __shfl_xor(s2, off);
  }
  __shared__ float ls[2], ls2[2];
  if ((b & 63) == 0) {
    ls[b >> 6] = s;
    ls2[b >> 6] = s2;
  }
  __syncthreads();
  if (b == 0) {
    float mu = (ls[0] + ls[1]) * (1.0f / 128.0f);
    float var = (ls2[0] + ls2[1]) * (1.0f / 128.0f) - mu * mu;
    float rs = rsqrtf(var + 1e-5f);
    float g = gamma[j] * rs;
    gs[j] = g;
    gb[j] = beta[j] - mu * g;
  }
}

// ---- fc2: one block per graph, block-reduce over j -----------------------
__global__ __launch_bounds__(256) void k_fc2(const float* __restrict__ z, const float* __restrict__ gs,
                                             const float* __restrict__ gb, const float* __restrict__ w2,
                                             const float* __restrict__ b2, float* __restrict__ out) {
  int bg = blockIdx.x;
  int t = threadIdx.x;
  float a0 = 0.f, a1 = 0.f;
  for (int j = t; j < 400; j += 256) {
    float zn = z[bg * 400 + j] * gs[j] + gb[j];
    float m = mish_f(zn);
    a0 += m * w2[j * 2];
    a1 += m * w2[j * 2 + 1];
  }
#pragma unroll
  for (int off = 1; off < 64; off <<= 1) {
    a0 += __shfl_xor(a0, off);
    a1 += __shfl_xor(a1, off);
  }
  __shared__ float s0[4], s1[4];
  if ((t & 63) == 0) {
    s0[t >> 6] = a0;
    s1[t >> 6] = a1;
  }
  __syncthreads();
  if (t == 0) {
    out[bg * 2 + 0] = b2[0] + s0[0] + s0[1] + s0[2] + s0[3];
    out[bg * 2 + 1] = b2[1] + s1[0] + s1[1] + s1[2] + s1[3];
  }
}

extern "C" void kernel_launch(void* const* d_in, const int* in_sizes, int n_in,
                              void* d_out, int out_size, void* d_ws, size_t ws_size,
                              hipStream_t stream) {
  (void)in_sizes; (void)n_in; (void)out_size; (void)ws_size;
  const float* x   = (const float*)d_in[0];
  const int*   ei  = (const int*)d_in[1];
  const float* ew  = (const float*)d_in[2];
  const float* c1w = (const float*)d_in[4];
  const float* c1b = (const float*)d_in[5];
  const float* c2w = (const float*)d_in[6];
  const float* c2b = (const float*)d_in[7];
  const float* rw  = (const float*)d_in[8];
  const float* rb  = (const float*)d_in[9];
  const float* f1w = (const float*)d_in[10];
  const float* bng = (const float*)d_in[12];
  const float* bnb = (const float*)d_in[13];
  const float* f2w = (const float*)d_in[14];
  const float* f2b = (const float*)d_in[15];
  float* out = (float*)d_out;

  char* ws = (char*)d_ws;
  size_t off = 0;
  auto alloc = [&](size_t bytes) {
    void* p = ws + off;
    off = (off + bytes + 255) & ~(size_t)255;
    return p;
  };
  float* dinv    = (float*)alloc((size_t)NN * 4);
  int*   cnt     = (int*)alloc((size_t)NN * 4);
  int*   rowptr  = (int*)alloc((size_t)(NN + 1) * 4);
  int*   bsum    = (int*)alloc(200 * 4);
  int*   boff    = (int*)alloc(200 * 4);
  unsigned* G    = (unsigned*)alloc((size_t)NBKT * NB * 4);  // 800 KB
  unsigned* btot = (unsigned*)alloc(NBKT * 4);
  unsigned* bbase= (unsigned*)alloc((NBKT + 1) * 4);
  unsigned* csr  = (unsigned*)alloc((size_t)NE * 4 + 64);    // 8.2 MB packed
  __half* A1     = (__half*)alloc((size_t)NN * F * 2);       // gemm out (fp16)
  __half* B1     = (__half*)alloc((size_t)NN * F * 2);       // agg out (fp16)
  _Float16* Wt1  = (_Float16*)alloc((size_t)400 * 128 * 2);
  _Float16* Wt2  = (_Float16*)alloc((size_t)128 * 128 * 2);
  float* o8      = (float*)alloc((size_t)NN * 8 * 4);
  float* z       = (float*)alloc((size_t)128 * 400 * 4);
  float* gs      = (float*)alloc(400 * 4);
  float* gb      = (float*)alloc(400 * 4);

  // E (16 MB) aliases A1+B1 (26 MB contiguous): E's last reader (k_fscat)
  // completes before gemm1 writes A1 (stream-ordered).
  uint2* E = (uint2*)A1;

  // 18 dispatches total (round-0 had 20).
  k_init<<<264, 256, 0, stream>>>(c1w, c2w, Wt1, Wt2, z);
  k_chist<<<NB, 256, 0, stream>>>(ei, G);
  k_bscan<<<NBKT, 64, 0, stream>>>(G, btot);
  k_bbase<<<1, 256, 0, stream>>>(btot, bbase);
  k_cscat<<<NB, 256, 0, stream>>>(ei, ew, G, bbase, E);
  k_fcnt<<<NBKT, 256, 0, stream>>>(E, bbase, cnt, dinv);
  k_scan1<<<NN / 256, 256, 0, stream>>>(cnt, bsum);
  k_scan2<<<1, 256, 0, stream>>>(bsum, boff, rowptr);
  k_scan3<<<NN / 256, 256, 0, stream>>>(cnt, boff, rowptr);
  k_fscat<<<NBKT, 256, 0, stream>>>(E, bbase, rowptr, dinv, csr);

  // conv1: h = x@W1 (MFMA, fp16 out) ; agg+bias+mish (fp16 out)
  k_gemm16<true><<<NN / 128, 256, 0, stream>>>(x, Wt1, A1, 400);
  k_agg<<<NN / 4, 256, 0, stream>>>((const __half2*)A1, rowptr, csr, dinv, c1b, (__half2*)B1);
  // conv2
  k_gemm16<false><<<NN / 128, 256, 0, stream>>>(B1, Wt2, A1, 128);
  k_agg<<<NN / 4, 256, 0, stream>>>((const __half2*)A1, rowptr, csr, dinv, c2b, (__half2*)B1);
  // readout -> feats (o8 flat IS feats[128][3200])
  k_ro<<<NN / 32, 256, 0, stream>>>((const __half2*)B1, rw, rb, o8);
  {
    dim3 g(25, 16);
    k_fc1<<<g, 448, 0, stream>>>(o8, f1w, z);
  }
  k_bn<<<400, 128, 0, stream>>>(z, bng, bnb, gs, gb);
  k_fc2<<<128, 256, 0, stream>>>(z, gs, gb, f2w, f2b, out);
}

// Round 7
// 456.701 us; speedup vs baseline: 1.3948x; 1.0352x over previous
//
#include <hip/hip_runtime.h>
#include <hip/hip_fp16.h>
#include <math.h>

#define NN 51200
#define NE 2048000
#define F 128
#define NB 1000        // coarse blocks
#define EPB 2048       // edges per coarse block (NB*EPB == NE)
#define NBKT 200       // coarse buckets (dst >> 8)
#define ECAP 12288     // per-bucket edge capacity (mean 10240, sigma ~101 -> 20 sigma)

typedef _Float16 half8 __attribute__((ext_vector_type(8)));
typedef float floatx4 __attribute__((ext_vector_type(4)));

__device__ __forceinline__ float mish_f(float x) {
  if (x > 20.0f) return x;
  float e = __expf(x);
  float w = 1.0f + e;
  w = w * w;
  return x * (w - 1.0f) / (w + 1.0f);
}

// ---- k_ic: chist (blocks 0..999) + W-transpose/z-zero (blocks 1000..1263)
__global__ __launch_bounds__(256) void k_ic(const int* __restrict__ ei, unsigned* __restrict__ G,
                                            const float* __restrict__ W1, const float* __restrict__ W2,
                                            _Float16* __restrict__ Wt1, _Float16* __restrict__ Wt2,
                                            float* __restrict__ z) {
  int bid = blockIdx.x, t = threadIdx.x;
  if (bid < NB) {
    __shared__ unsigned hist[NBKT];
    for (int i = t; i < NBKT; i += 256) hist[i] = 0u;
    __syncthreads();
    int base = bid * EPB;
    for (int it = 0; it < EPB; it += 256) {
      int dst = ei[NE + base + it + t];
      atomicAdd(&hist[dst >> 8], 1u);
    }
    __syncthreads();
    for (int i = t; i < NBKT; i += 256) G[(size_t)i * NB + bid] = hist[i];
  } else {
    int idx = (bid - NB) * 256 + t;  // 0..67583 = 51200 (W1) + 16384 (W2)
    if (idx < 51200) {
      int k = idx >> 7, n = idx & 127;
      Wt1[n * 400 + k] = (_Float16)W1[idx];
      z[idx] = 0.0f;  // z is 128*400 == 51200 floats
    } else {
      int i2 = idx - 51200;
      int k = i2 >> 7, n = i2 & 127;
      Wt2[n * 128 + k] = (_Float16)W2[i2];
    }
  }
}

// ---- per-bucket exclusive scan over the NB block counts (1 wave/bucket) --
__global__ __launch_bounds__(64) void k_bscan(unsigned* __restrict__ G, unsigned* __restrict__ btot) {
  int b = blockIdx.x, l = threadIdx.x;
  unsigned base = (unsigned)l * 16;
  unsigned loc[16];
  unsigned s = 0;
#pragma unroll
  for (int i = 0; i < 16; ++i) {
    unsigned idx = base + i;
    unsigned x = (idx < NB) ? G[(size_t)b * NB + idx] : 0u;
    loc[i] = s;
    s += x;
  }
  unsigned run = s;
#pragma unroll
  for (int off = 1; off < 64; off <<= 1) {
    unsigned y = __shfl_up(run, off);
    if (l >= off) run += y;
  }
  unsigned excl = run - s;
#pragma unroll
  for (int i = 0; i < 16; ++i) {
    unsigned idx = base + i;
    if (idx < NB) G[(size_t)b * NB + idx] = excl + loc[i];
  }
  if (l == 63) btot[b] = run;
}

// ---- scatter edges into bucket-grouped E at static bases b*ECAP ----------
__global__ __launch_bounds__(256) void k_cscat(const int* __restrict__ ei, const float* __restrict__ ew,
                                               const unsigned* __restrict__ G,
                                               uint2* __restrict__ E) {
  __shared__ unsigned cur[NBKT];
  int blk = blockIdx.x, t = threadIdx.x;
  for (int i = t; i < NBKT; i += 256) cur[i] = (unsigned)i * ECAP + G[(size_t)i * NB + blk];
  __syncthreads();
  int base = blk * EPB;
  for (int it = 0; it < EPB; it += 256) {
    int e = base + it + t;
    int dst = ei[NE + e];
    int src = ei[e];
    float w = ew[e];
    unsigned pos = atomicAdd(&cur[dst >> 8], 1u);
    E[pos] = make_uint2((unsigned)src | ((unsigned)(dst & 255) << 16), __float_as_uint(w));
  }
}

// ---- k_fprep: per-bucket count+degsum -> LDS scan -> bounds/dinv -> scatter
// csr entry packed 4B: src (16b) | fp16(ew) << 16 (NO dinv -- folded into
// the gemm epilogue row-scale, which makes this kernel self-contained).
__global__ __launch_bounds__(256) void k_fprep(const uint2* __restrict__ E, const unsigned* __restrict__ btot,
                                               int2* __restrict__ bounds, float* __restrict__ dinv,
                                               unsigned* __restrict__ csr) {
  __shared__ unsigned lc[256];
  __shared__ float ld[256];
  __shared__ int curs[256];
  __shared__ int ws4[4];
  int b = blockIdx.x, t = threadIdx.x;
  lc[t] = 0u;
  ld[t] = 0.f;
  __syncthreads();
  unsigned e0 = (unsigned)b * ECAP, e1 = e0 + btot[b];
  for (unsigned e = e0 + t; e < e1; e += 256) {
    uint2 v = E[e];
    unsigned node = (v.x >> 16) & 255u;
    atomicAdd(&lc[node], 1u);
    atomicAdd(&ld[node], __uint_as_float(v.y));
  }
  __syncthreads();
  // exclusive scan of lc[0..255]
  int lane = t & 63, wid = t >> 6;
  int cv = (int)lc[t];
  int x = cv;
#pragma unroll
  for (int off = 1; off < 64; off <<= 1) {
    int y = __shfl_up(x, off);
    if (lane >= off) x += y;
  }
  if (lane == 63) ws4[wid] = x;
  __syncthreads();
  int woff = 0;
  for (int k = 0; k < wid; ++k) woff += ws4[k];
  int start = (int)e0 + woff + x - cv;
  bounds[b * 256 + t] = make_int2(start, start + cv);
  dinv[b * 256 + t] = rsqrtf(ld[t] + 1.0f);  // +1 = self-loop weight
  curs[t] = start;
  __syncthreads();
  for (unsigned e = e0 + t; e < e1; e += 256) {
    uint2 v = E[e];
    unsigned node = (v.x >> 16) & 255u;
    unsigned src = v.x & 0xFFFFu;
    int p = atomicAdd(&curs[node], 1);
    unsigned pk = src | ((unsigned)__half_as_ushort(__float2half_rn(__uint_as_float(v.y))) << 16);
    __builtin_nontemporal_store(pk, &csr[p]);
  }
}

// ---- MFMA GEMM with dinv row-scale epilogue: C[r] = fp16(dinv[r]*(A@W)[r])
template <bool A_IS_F32>
__global__ __launch_bounds__(256) void k_gemm16(const void* __restrict__ Av,
                                                const _Float16* __restrict__ Wt,
                                                const float* __restrict__ dinv,
                                                __half* __restrict__ C, int K) {
  __shared__ _Float16 As[128][40];
  __shared__ _Float16 Bs[128][40];
  int t = threadIdx.x;
  int bm = blockIdx.x * 128;
  int w = t >> 6, l = t & 63, rr = l & 15, q = l >> 4;
  int si = t >> 1, sj = (t & 1) * 16;

  floatx4 acc[2][8];
#pragma unroll
  for (int a = 0; a < 2; ++a)
#pragma unroll
    for (int b = 0; b < 8; ++b) acc[a][b] = (floatx4){0.f, 0.f, 0.f, 0.f};

  for (int k0 = 0; k0 < K; k0 += 32) {
    if (A_IS_F32) {
      const float* A = (const float*)Av;
      half8 h0, h1;
      if (k0 + sj < K) {
        const float* ap = A + (size_t)(bm + si) * K + k0 + sj;
        float4 v0 = *(const float4*)(ap + 0);
        float4 v1 = *(const float4*)(ap + 4);
        float4 v2 = *(const float4*)(ap + 8);
        float4 v3 = *(const float4*)(ap + 12);
        h0 = (half8){(_Float16)v0.x, (_Float16)v0.y, (_Float16)v0.z, (_Float16)v0.w,
                     (_Float16)v1.x, (_Float16)v1.y, (_Float16)v1.z, (_Float16)v1.w};
        h1 = (half8){(_Float16)v2.x, (_Float16)v2.y, (_Float16)v2.z, (_Float16)v2.w,
                     (_Float16)v3.x, (_Float16)v3.y, (_Float16)v3.z, (_Float16)v3.w};
      } else {
        h0 = (half8){0, 0, 0, 0, 0, 0, 0, 0};
        h1 = h0;
      }
      *(half8*)&As[si][sj] = h0;
      *(half8*)&As[si][sj + 8] = h1;
    } else {
      const __half* A = (const __half*)Av;
      uint4 u0, u1;
      if (k0 + sj < K) {
        const __half* ap = A + (size_t)(bm + si) * K + k0 + sj;
        u0 = *(const uint4*)ap;
        u1 = *(const uint4*)(ap + 8);
      } else {
        u0 = make_uint4(0, 0, 0, 0);
        u1 = u0;
      }
      *(uint4*)&As[si][sj] = u0;
      *(uint4*)&As[si][sj + 8] = u1;
    }
    {
      uint4 u0, u1;
      if (k0 + sj < K) {
        const _Float16* wp = Wt + (size_t)si * K + k0 + sj;
        u0 = *(const uint4*)wp;
        u1 = *(const uint4*)(wp + 8);
      } else {
        u0 = make_uint4(0, 0, 0, 0);
        u1 = u0;
      }
      *(uint4*)&Bs[si][sj] = u0;
      *(uint4*)&Bs[si][sj + 8] = u1;
    }
    __syncthreads();

    half8 a0 = *(const half8*)&As[w * 32 + rr][q * 8];
    half8 a1 = *(const half8*)&As[w * 32 + 16 + rr][q * 8];
#pragma unroll
    for (int nt = 0; nt < 8; ++nt) {
      half8 b = *(const half8*)&Bs[nt * 16 + rr][q * 8];
      acc[0][nt] = __builtin_amdgcn_mfma_f32_16x16x32_f16(a0, b, acc[0][nt], 0, 0, 0);
      acc[1][nt] = __builtin_amdgcn_mfma_f32_16x16x32_f16(a1, b, acc[1][nt], 0, 0, 0);
    }
    __syncthreads();
  }
#pragma unroll
  for (int mt = 0; mt < 2; ++mt) {
    float dv[4];
#pragma unroll
    for (int r4 = 0; r4 < 4; ++r4) dv[r4] = dinv[bm + w * 32 + mt * 16 + q * 4 + r4];
#pragma unroll
    for (int nt = 0; nt < 8; ++nt)
#pragma unroll
      for (int r4 = 0; r4 < 4; ++r4) {
        int row = bm + w * 32 + mt * 16 + q * 4 + r4;
        C[(size_t)row * 128 + nt * 16 + rr] = __float2half(dv[r4] * acc[mt][nt][r4]);
      }
  }
}

// ---- conv1 agg: out[n] = mish(di*(sum ew*h"[src] + h"[n]) + bias) --------
// h" rows are pre-scaled by dinv in the gemm epilogue.
__global__ __launch_bounds__(256) void k_agg(const __half2* __restrict__ h, const int2* __restrict__ bounds,
                                             const unsigned* __restrict__ csr, const float* __restrict__ dinv,
                                             const float* __restrict__ bias, __half2* __restrict__ out) {
  unsigned lane = threadIdx.x & 63u;
  int n = blockIdx.x * 4 + (threadIdx.x >> 6);
  float di = dinv[n];
  float2 self = __half22float2(h[((unsigned)n << 6) + lane]);
  float sx = 0.f, sy = 0.f;
  int2 bd = bounds[n];
  int p = __builtin_amdgcn_readfirstlane(bd.x);
  int p1 = __builtin_amdgcn_readfirstlane(bd.y);
  for (; p + 16 <= p1; p += 16) {
    unsigned c[16];
#pragma unroll
    for (int u = 0; u < 16; ++u) c[u] = csr[p + u];
    float2 f[16];
#pragma unroll
    for (int u = 0; u < 16; ++u) f[u] = __half22float2(h[((c[u] & 0xFFFFu) << 6) + lane]);
#pragma unroll
    for (int u = 0; u < 16; ++u) {
      float w = __half2float(__ushort_as_half((unsigned short)(c[u] >> 16)));
      sx += w * f[u].x;
      sy += w * f[u].y;
    }
  }
  for (; p + 4 <= p1; p += 4) {
    unsigned c[4];
#pragma unroll
    for (int u = 0; u < 4; ++u) c[u] = csr[p + u];
    float2 f[4];
#pragma unroll
    for (int u = 0; u < 4; ++u) f[u] = __half22float2(h[((c[u] & 0xFFFFu) << 6) + lane]);
#pragma unroll
    for (int u = 0; u < 4; ++u) {
      float w = __half2float(__ushort_as_half((unsigned short)(c[u] >> 16)));
      sx += w * f[u].x;
      sy += w * f[u].y;
    }
  }
  for (; p < p1; ++p) {
    unsigned c0 = csr[p];
    float2 f0 = __half22float2(h[((c0 & 0xFFFFu) << 6) + lane]);
    float w = __half2float(__ushort_as_half((unsigned short)(c0 >> 16)));
    sx += w * f0.x;
    sy += w * f0.y;
  }
  float2 bb = ((const float2*)bias)[lane];
  float ax = di * (sx + self.x) + bb.x;
  float ay = di * (sy + self.y) + bb.y;
  out[((unsigned)n << 6) + lane] = __floats2half2_rn(mish_f(ax), mish_f(ay));
}

// ---- conv2 agg FUSED with readout: o8[n][k] directly ---------------------
// After computing m = mish(conv2 out), reduce m@ro_w across the wave
// (each lane holds 2 of the 128 features) and write 8 floats per node.
__global__ __launch_bounds__(256) void k_agg2ro(const __half2* __restrict__ h, const int2* __restrict__ bounds,
                                                const unsigned* __restrict__ csr, const float* __restrict__ dinv,
                                                const float* __restrict__ bias, const float* __restrict__ rw,
                                                const float* __restrict__ rb, float* __restrict__ o8) {
  __shared__ float wl[128 * 8];
  int t = threadIdx.x;
  for (int i = t; i < 1024; i += 256) wl[i] = rw[i];
  __syncthreads();
  unsigned lane = t & 63u;
  int n = blockIdx.x * 4 + (t >> 6);
  float di = dinv[n];
  float2 self = __half22float2(h[((unsigned)n << 6) + lane]);
  float sx = 0.f, sy = 0.f;
  int2 bd = bounds[n];
  int p = __builtin_amdgcn_readfirstlane(bd.x);
  int p1 = __builtin_amdgcn_readfirstlane(bd.y);
  for (; p + 16 <= p1; p += 16) {
    unsigned c[16];
#pragma unroll
    for (int u = 0; u < 16; ++u) c[u] = csr[p + u];
    float2 f[16];
#pragma unroll
    for (int u = 0; u < 16; ++u) f[u] = __half22float2(h[((c[u] & 0xFFFFu) << 6) + lane]);
#pragma unroll
    for (int u = 0; u < 16; ++u) {
      float w = __half2float(__ushort_as_half((unsigned short)(c[u] >> 16)));
      sx += w * f[u].x;
      sy += w * f[u].y;
    }
  }
  for (; p + 4 <= p1; p += 4) {
    unsigned c[4];
#pragma unroll
    for (int u = 0; u < 4; ++u) c[u] = csr[p + u];
    float2 f[4];
#pragma unroll
    for (int u = 0; u < 4; ++u) f[u] = __half22float2(h[((c[u] & 0xFFFFu) << 6) + lane]);
#pragma unroll
    for (int u = 0; u < 4; ++u) {
      float w = __half2float(__ushort_as_half((unsigned short)(c[u] >> 16)));
      sx += w * f[u].x;
      sy += w * f[u].y;
    }
  }
  for (; p < p1; ++p) {
    unsigned c0 = csr[p];
    float2 f0 = __half22float2(h[((c0 & 0xFFFFu) << 6) + lane]);
    float w = __half2float(__ushort_as_half((unsigned short)(c0 >> 16)));
    sx += w * f0.x;
    sy += w * f0.y;
  }
  float2 bb = ((const float2*)bias)[lane];
  float m0 = mish_f(di * (sx + self.x) + bb.x);
  float m1 = mish_f(di * (sy + self.y) + bb.y);
  // readout: p8[k] = sum over 128 features of m[f]*rw[f][k]
  float p8[8];
#pragma unroll
  for (int k = 0; k < 8; ++k)
    p8[k] = m0 * wl[(2 * lane) * 8 + k] + m1 * wl[(2 * lane + 1) * 8 + k];
#pragma unroll
  for (int off = 1; off < 64; off <<= 1)
#pragma unroll
    for (int k = 0; k < 8; ++k) p8[k] += __shfl_xor(p8[k], off);
  if (lane < 8) o8[(size_t)n * 8 + lane] = mish_f(p8[lane] + rb[lane]);
}

// ---- fc1 split-K: z += feats[g, kc:kc+128] @ w[kc:kc+128, :] -------------
// fc1 bias omitted: BatchNorm (training mode) is invariant to a per-feature
// constant added to z (it shifts mu equally).
__global__ __launch_bounds__(448) void k_fc1(const float* __restrict__ feats, const float* __restrict__ w,
                                             float* __restrict__ z) {
  __shared__ float fs[8][128];
  int t = threadIdx.x;
  int kc = blockIdx.x * 128;
  int g0 = blockIdx.y * 8;
  for (int i = t; i < 1024; i += 448) {
    int g = i >> 7, k = i & 127;
    fs[g][k] = feats[(size_t)(g0 + g) * 3200 + kc + k];
  }
  __syncthreads();
  if (t < 400) {
    float a[8];
#pragma unroll
    for (int g = 0; g < 8; ++g) a[g] = 0.0f;
    for (int k = 0; k < 128; ++k) {
      float wv = w[(size_t)(kc + k) * 400 + t];
#pragma unroll
      for (int g = 0; g < 8; ++g) a[g] += fs[g][k] * wv;
    }
#pragma unroll
    for (int g = 0; g < 8; ++g) atomicAdd(&z[(size_t)(g0 + g) * 400 + t], a[g]);
  }
}

// ---- batchnorm stats: one block per feature, thread = batch element ------
__global__ __launch_bounds__(128) void k_bn(const float* __restrict__ z, const float* __restrict__ gamma,
                                            const float* __restrict__ beta, float* __restrict__ gs,
                                            float* __restrict__ gb) {
  int j = blockIdx.x;
  int b = threadIdx.x;
  float v = z[b * 400 + j];
  float s = v, s2 = v * v;
#pragma unroll
  for (int off = 1; off < 64; off <<= 1) {
    s += __shfl_xor(s, off);
    s2 += __shfl_xor(s2, off);
  }
  __shared__ float ls[2], ls2[2];
  if ((b & 63) == 0) {
    ls[b >> 6] = s;
    ls2[b >> 6] = s2;
  }
  __syncthreads();
  if (b == 0) {
    float mu = (ls[0] + ls[1]) * (1.0f / 128.0f);
    float var = (ls2[0] + ls2[1]) * (1.0f / 128.0f) - mu * mu;
    float rs = rsqrtf(var + 1e-5f);
    float g = gamma[j] * rs;
    gs[j] = g;
    gb[j] = beta[j] - mu * g;
  }
}

// ---- fc2: one block per graph, block-reduce over j -----------------------
__global__ __launch_bounds__(256) void k_fc2(const float* __restrict__ z, const float* __restrict__ gs,
                                             const float* __restrict__ gb, const float* __restrict__ w2,
                                             const float* __restrict__ b2, float* __restrict__ out) {
  int bg = blockIdx.x;
  int t = threadIdx.x;
  float a0 = 0.f, a1 = 0.f;
  for (int j = t; j < 400; j += 256) {
    float zn = z[bg * 400 + j] * gs[j] + gb[j];
    float m = mish_f(zn);
    a0 += m * w2[j * 2];
    a1 += m * w2[j * 2 + 1];
  }
#pragma unroll
  for (int off = 1; off < 64; off <<= 1) {
    a0 += __shfl_xor(a0, off);
    a1 += __shfl_xor(a1, off);
  }
  __shared__ float s0[4], s1[4];
  if ((t & 63) == 0) {
    s0[t >> 6] = a0;
    s1[t >> 6] = a1;
  }
  __syncthreads();
  if (t == 0) {
    out[bg * 2 + 0] = b2[0] + s0[0] + s0[1] + s0[2] + s0[3];
    out[bg * 2 + 1] = b2[1] + s1[0] + s1[1] + s1[2] + s1[3];
  }
}

extern "C" void kernel_launch(void* const* d_in, const int* in_sizes, int n_in,
                              void* d_out, int out_size, void* d_ws, size_t ws_size,
                              hipStream_t stream) {
  (void)in_sizes; (void)n_in; (void)out_size; (void)ws_size;
  const float* x   = (const float*)d_in[0];
  const int*   ei  = (const int*)d_in[1];
  const float* ew  = (const float*)d_in[2];
  const float* c1w = (const float*)d_in[4];
  const float* c1b = (const float*)d_in[5];
  const float* c2w = (const float*)d_in[6];
  const float* c2b = (const float*)d_in[7];
  const float* rw  = (const float*)d_in[8];
  const float* rb  = (const float*)d_in[9];
  const float* f1w = (const float*)d_in[10];
  const float* bng = (const float*)d_in[12];
  const float* bnb = (const float*)d_in[13];
  const float* f2w = (const float*)d_in[14];
  const float* f2b = (const float*)d_in[15];
  float* out = (float*)d_out;

  char* ws = (char*)d_ws;
  size_t off = 0;
  auto alloc = [&](size_t bytes) {
    void* p = ws + off;
    off = (off + bytes + 255) & ~(size_t)255;
    return p;
  };
  float* dinv    = (float*)alloc((size_t)NN * 4);
  int2*  bounds  = (int2*)alloc((size_t)NN * 8);
  unsigned* G    = (unsigned*)alloc((size_t)NBKT * NB * 4);  // 800 KB
  unsigned* btot = (unsigned*)alloc(NBKT * 4);
  unsigned* csr  = (unsigned*)alloc((size_t)NBKT * ECAP * 4);  // 9.8 MB packed
  __half* A1     = (__half*)alloc((size_t)NN * F * 2);       // gemm out (fp16, dinv-scaled)
  __half* B1     = (__half*)alloc((size_t)NN * F * 2);       // agg1 out (fp16)
  _Float16* Wt1  = (_Float16*)alloc((size_t)400 * 128 * 2);
  _Float16* Wt2  = (_Float16*)alloc((size_t)128 * 128 * 2);
  float* o8      = (float*)alloc((size_t)NN * 8 * 4);
  float* z       = (float*)alloc((size_t)128 * 400 * 4);
  float* gs      = (float*)alloc(400 * 4);
  float* gb      = (float*)alloc(400 * 4);

  // E (19.7 MB = NBKT*ECAP*8) aliases A1+B1 (26.2 MB contiguous): E's last
  // reader (k_fprep) completes before gemm1 writes A1 (stream-ordered).
  uint2* E = (uint2*)A1;

  // 11 dispatches total (round-6 had 18).
  k_ic<<<NB + 264, 256, 0, stream>>>(ei, G, c1w, c2w, Wt1, Wt2, z);
  k_bscan<<<NBKT, 64, 0, stream>>>(G, btot);
  k_cscat<<<NB, 256, 0, stream>>>(ei, ew, G, E);
  k_fprep<<<NBKT, 256, 0, stream>>>(E, btot, bounds, dinv, csr);

  // conv1: h" = dinv*(x@W1) (MFMA) ; agg+bias+mish
  k_gemm16<true><<<NN / 128, 256, 0, stream>>>(x, Wt1, dinv, A1, 400);
  k_agg<<<NN / 4, 256, 0, stream>>>((const __half2*)A1, bounds, csr, dinv, c1b, (__half2*)B1);
  // conv2 + fused readout -> o8 (feats)
  k_gemm16<false><<<NN / 128, 256, 0, stream>>>(B1, Wt2, dinv, A1, 128);
  k_agg2ro<<<NN / 4, 256, 0, stream>>>((const __half2*)A1, bounds, csr, dinv, c2b, rw, rb, o8);

  {
    dim3 g(25, 16);
    k_fc1<<<g, 448, 0, stream>>>(o8, f1w, z);
  }
  k_bn<<<400, 128, 0, stream>>>(z, bng, bnb, gs, gb);
  k_fc2<<<128, 256, 0, stream>>>(z, gs, gb, f2w, f2b, out);
}

// Round 8
// 409.475 us; speedup vs baseline: 1.5557x; 1.1153x over previous
//
#include <hip/hip_runtime.h>
#include <hip/hip_fp16.h>
#include <math.h>

#define NN 51200
#define NE 2048000
#define F 128
#define NB 1000        // coarse blocks
#define EPB 2048       // edges per coarse block (NB*EPB == NE)
#define NBKT 200       // coarse buckets (dst >> 8)
#define ECAP 12288     // per-bucket edge capacity (mean 10240, sigma ~101 -> 20 sigma)

typedef _Float16 half8 __attribute__((ext_vector_type(8)));
typedef float floatx4 __attribute__((ext_vector_type(4)));

__device__ __forceinline__ float mish_f(float x) {
  if (x > 20.0f) return x;
  float e = __expf(x);
  float w = 1.0f + e;
  w = w * w;
  return x * (w - 1.0f) / (w + 1.0f);
}

// ---- k_ic: chist (blocks 0..999) + W-transpose/z-zero (blocks 1000..1263)
__global__ __launch_bounds__(256) void k_ic(const int* __restrict__ ei, unsigned* __restrict__ G,
                                            const float* __restrict__ W1, const float* __restrict__ W2,
                                            _Float16* __restrict__ Wt1, _Float16* __restrict__ Wt2,
                                            float* __restrict__ z) {
  int bid = blockIdx.x, t = threadIdx.x;
  if (bid < NB) {
    __shared__ unsigned hist[NBKT];
    for (int i = t; i < NBKT; i += 256) hist[i] = 0u;
    __syncthreads();
    int base = bid * EPB;
    for (int it = 0; it < EPB; it += 256) {
      int dst = ei[NE + base + it + t];
      atomicAdd(&hist[dst >> 8], 1u);
    }
    __syncthreads();
    for (int i = t; i < NBKT; i += 256) G[(size_t)i * NB + bid] = hist[i];
  } else {
    int idx = (bid - NB) * 256 + t;  // 0..67583 = 51200 (W1) + 16384 (W2)
    if (idx < 51200) {
      int k = idx >> 7, n = idx & 127;
      Wt1[n * 400 + k] = (_Float16)W1[idx];
      z[idx] = 0.0f;  // z is 128*400 == 51200 floats
    } else {
      int i2 = idx - 51200;
      int k = i2 >> 7, n = i2 & 127;
      Wt2[n * 128 + k] = (_Float16)W2[i2];
    }
  }
}

// ---- per-bucket exclusive scan over the NB block counts (1 wave/bucket) --
__global__ __launch_bounds__(64) void k_bscan(unsigned* __restrict__ G, unsigned* __restrict__ btot) {
  int b = blockIdx.x, l = threadIdx.x;
  unsigned base = (unsigned)l * 16;
  unsigned loc[16];
  unsigned s = 0;
#pragma unroll
  for (int i = 0; i < 16; ++i) {
    unsigned idx = base + i;
    unsigned x = (idx < NB) ? G[(size_t)b * NB + idx] : 0u;
    loc[i] = s;
    s += x;
  }
  unsigned run = s;
#pragma unroll
  for (int off = 1; off < 64; off <<= 1) {
    unsigned y = __shfl_up(run, off);
    if (l >= off) run += y;
  }
  unsigned excl = run - s;
#pragma unroll
  for (int i = 0; i < 16; ++i) {
    unsigned idx = base + i;
    if (idx < NB) G[(size_t)b * NB + idx] = excl + loc[i];
  }
  if (l == 63) btot[b] = run;
}

// ---- scatter edges into bucket-grouped E at static bases b*ECAP ----------
__global__ __launch_bounds__(256) void k_cscat(const int* __restrict__ ei, const float* __restrict__ ew,
                                               const unsigned* __restrict__ G,
                                               uint2* __restrict__ E) {
  __shared__ unsigned cur[NBKT];
  int blk = blockIdx.x, t = threadIdx.x;
  for (int i = t; i < NBKT; i += 256) cur[i] = (unsigned)i * ECAP + G[(size_t)i * NB + blk];
  __syncthreads();
  int base = blk * EPB;
  for (int it = 0; it < EPB; it += 256) {
    int e = base + it + t;
    int dst = ei[NE + e];
    int src = ei[e];
    float w = ew[e];
    unsigned pos = atomicAdd(&cur[dst >> 8], 1u);
    E[pos] = make_uint2((unsigned)src | ((unsigned)(dst & 255) << 16), __float_as_uint(w));
  }
}

// ---- k_fprep: per-bucket count+degsum -> LDS scan -> bounds/dinv -> scatter
// csr entry packed 4B: src (16b) | fp16(ew) << 16 (NO dinv -- folded into
// the gemm epilogue row-scale). 512 threads/block halves the two E-pass
// latencies. Plain stores for csr: scattered 4B writes coalesce in L2
// (nt stores forced 64B partial-line HBM writes -> 139MB WRITE, round-7 bug).
__global__ __launch_bounds__(512) void k_fprep(const uint2* __restrict__ E, const unsigned* __restrict__ btot,
                                               int2* __restrict__ bounds, float* __restrict__ dinv,
                                               unsigned* __restrict__ csr) {
  __shared__ unsigned lc[256];
  __shared__ float ld[256];
  __shared__ int curs[256];
  __shared__ int ws4[4];
  __shared__ int starts[256];
  int b = blockIdx.x, t = threadIdx.x;
  if (t < 256) {
    lc[t] = 0u;
    ld[t] = 0.f;
  }
  __syncthreads();
  unsigned e0 = (unsigned)b * ECAP, e1 = e0 + btot[b];
  for (unsigned e = e0 + t; e < e1; e += 512) {
    uint2 v = E[e];
    unsigned node = (v.x >> 16) & 255u;
    atomicAdd(&lc[node], 1u);
    atomicAdd(&ld[node], __uint_as_float(v.y));
  }
  __syncthreads();
  // exclusive scan of lc[0..255] (first 256 threads)
  if (t < 256) {
    int lane = t & 63, wid = t >> 6;
    int cv = (int)lc[t];
    int x = cv;
#pragma unroll
    for (int off = 1; off < 64; off <<= 1) {
      int y = __shfl_up(x, off);
      if (lane >= off) x += y;
    }
    if (lane == 63) ws4[wid] = x;
    __syncthreads();
    int woff = 0;
    for (int k = 0; k < wid; ++k) woff += ws4[k];
    int start = (int)e0 + woff + x - cv;
    bounds[b * 256 + t] = make_int2(start, start + cv);
    dinv[b * 256 + t] = rsqrtf(ld[t] + 1.0f);  // +1 = self-loop weight
    curs[t] = start;
    starts[t] = start;
  } else {
    __syncthreads();
  }
  __syncthreads();
  for (unsigned e = e0 + t; e < e1; e += 512) {
    uint2 v = E[e];
    unsigned node = (v.x >> 16) & 255u;
    unsigned src = v.x & 0xFFFFu;
    int p = atomicAdd(&curs[node], 1);
    unsigned pk = src | ((unsigned)__half_as_ushort(__float2half_rn(__uint_as_float(v.y))) << 16);
    csr[p] = pk;
  }
  (void)starts;
}

// ---- MFMA GEMM with dinv row-scale epilogue: C[r] = fp16(dinv[r]*(A@W)[r])
template <bool A_IS_F32>
__global__ __launch_bounds__(256) void k_gemm16(const void* __restrict__ Av,
                                                const _Float16* __restrict__ Wt,
                                                const float* __restrict__ dinv,
                                                __half* __restrict__ C, int K) {
  __shared__ _Float16 As[128][40];
  __shared__ _Float16 Bs[128][40];
  int t = threadIdx.x;
  int bm = blockIdx.x * 128;
  int w = t >> 6, l = t & 63, rr = l & 15, q = l >> 4;
  int si = t >> 1, sj = (t & 1) * 16;

  floatx4 acc[2][8];
#pragma unroll
  for (int a = 0; a < 2; ++a)
#pragma unroll
    for (int b = 0; b < 8; ++b) acc[a][b] = (floatx4){0.f, 0.f, 0.f, 0.f};

  for (int k0 = 0; k0 < K; k0 += 32) {
    if (A_IS_F32) {
      const float* A = (const float*)Av;
      half8 h0, h1;
      if (k0 + sj < K) {
        const float* ap = A + (size_t)(bm + si) * K + k0 + sj;
        float4 v0 = *(const float4*)(ap + 0);
        float4 v1 = *(const float4*)(ap + 4);
        float4 v2 = *(const float4*)(ap + 8);
        float4 v3 = *(const float4*)(ap + 12);
        h0 = (half8){(_Float16)v0.x, (_Float16)v0.y, (_Float16)v0.z, (_Float16)v0.w,
                     (_Float16)v1.x, (_Float16)v1.y, (_Float16)v1.z, (_Float16)v1.w};
        h1 = (half8){(_Float16)v2.x, (_Float16)v2.y, (_Float16)v2.z, (_Float16)v2.w,
                     (_Float16)v3.x, (_Float16)v3.y, (_Float16)v3.z, (_Float16)v3.w};
      } else {
        h0 = (half8){0, 0, 0, 0, 0, 0, 0, 0};
        h1 = h0;
      }
      *(half8*)&As[si][sj] = h0;
      *(half8*)&As[si][sj + 8] = h1;
    } else {
      const __half* A = (const __half*)Av;
      uint4 u0, u1;
      if (k0 + sj < K) {
        const __half* ap = A + (size_t)(bm + si) * K + k0 + sj;
        u0 = *(const uint4*)ap;
        u1 = *(const uint4*)(ap + 8);
      } else {
        u0 = make_uint4(0, 0, 0, 0);
        u1 = u0;
      }
      *(uint4*)&As[si][sj] = u0;
      *(uint4*)&As[si][sj + 8] = u1;
    }
    {
      uint4 u0, u1;
      if (k0 + sj < K) {
        const _Float16* wp = Wt + (size_t)si * K + k0 + sj;
        u0 = *(const uint4*)wp;
        u1 = *(const uint4*)(wp + 8);
      } else {
        u0 = make_uint4(0, 0, 0, 0);
        u1 = u0;
      }
      *(uint4*)&Bs[si][sj] = u0;
      *(uint4*)&Bs[si][sj + 8] = u1;
    }
    __syncthreads();

    half8 a0 = *(const half8*)&As[w * 32 + rr][q * 8];
    half8 a1 = *(const half8*)&As[w * 32 + 16 + rr][q * 8];
#pragma unroll
    for (int nt = 0; nt < 8; ++nt) {
      half8 b = *(const half8*)&Bs[nt * 16 + rr][q * 8];
      acc[0][nt] = __builtin_amdgcn_mfma_f32_16x16x32_f16(a0, b, acc[0][nt], 0, 0, 0);
      acc[1][nt] = __builtin_amdgcn_mfma_f32_16x16x32_f16(a1, b, acc[1][nt], 0, 0, 0);
    }
    __syncthreads();
  }
#pragma unroll
  for (int mt = 0; mt < 2; ++mt) {
    float dv[4];
#pragma unroll
    for (int r4 = 0; r4 < 4; ++r4) dv[r4] = dinv[bm + w * 32 + mt * 16 + q * 4 + r4];
#pragma unroll
    for (int nt = 0; nt < 8; ++nt)
#pragma unroll
      for (int r4 = 0; r4 < 4; ++r4) {
        int row = bm + w * 32 + mt * 16 + q * 4 + r4;
        C[(size_t)row * 128 + nt * 16 + rr] = __float2half(dv[r4] * acc[mt][nt][r4]);
      }
  }
}

// ---- conv1 agg: out[n] = mish(di*(sum ew*h"[src] + h"[n]) + bias) --------
// h" rows are pre-scaled by dinv in the gemm epilogue.
__global__ __launch_bounds__(256) void k_agg(const __half2* __restrict__ h, const int2* __restrict__ bounds,
                                             const unsigned* __restrict__ csr, const float* __restrict__ dinv,
                                             const float* __restrict__ bias, __half2* __restrict__ out) {
  unsigned lane = threadIdx.x & 63u;
  int n = blockIdx.x * 4 + (threadIdx.x >> 6);
  float di = dinv[n];
  float2 self = __half22float2(h[((unsigned)n << 6) + lane]);
  float sx = 0.f, sy = 0.f;
  int2 bd = bounds[n];
  int p = __builtin_amdgcn_readfirstlane(bd.x);
  int p1 = __builtin_amdgcn_readfirstlane(bd.y);
  for (; p + 16 <= p1; p += 16) {
    unsigned c[16];
#pragma unroll
    for (int u = 0; u < 16; ++u) c[u] = csr[p + u];
    float2 f[16];
#pragma unroll
    for (int u = 0; u < 16; ++u) f[u] = __half22float2(h[((c[u] & 0xFFFFu) << 6) + lane]);
#pragma unroll
    for (int u = 0; u < 16; ++u) {
      float w = __half2float(__ushort_as_half((unsigned short)(c[u] >> 16)));
      sx += w * f[u].x;
      sy += w * f[u].y;
    }
  }
  for (; p + 4 <= p1; p += 4) {
    unsigned c[4];
#pragma unroll
    for (int u = 0; u < 4; ++u) c[u] = csr[p + u];
    float2 f[4];
#pragma unroll
    for (int u = 0; u < 4; ++u) f[u] = __half22float2(h[((c[u] & 0xFFFFu) << 6) + lane]);
#pragma unroll
    for (int u = 0; u < 4; ++u) {
      float w = __half2float(__ushort_as_half((unsigned short)(c[u] >> 16)));
      sx += w * f[u].x;
      sy += w * f[u].y;
    }
  }
  for (; p < p1; ++p) {
    unsigned c0 = csr[p];
    float2 f0 = __half22float2(h[((c0 & 0xFFFFu) << 6) + lane]);
    float w = __half2float(__ushort_as_half((unsigned short)(c0 >> 16)));
    sx += w * f0.x;
    sy += w * f0.y;
  }
  float2 bb = ((const float2*)bias)[lane];
  float ax = di * (sx + self.x) + bb.x;
  float ay = di * (sy + self.y) + bb.y;
  out[((unsigned)n << 6) + lane] = __floats2half2_rn(mish_f(ax), mish_f(ay));
}

// ---- conv2 agg FUSED with readout: o8[n][k] directly ---------------------
__global__ __launch_bounds__(256) void k_agg2ro(const __half2* __restrict__ h, const int2* __restrict__ bounds,
                                                const unsigned* __restrict__ csr, const float* __restrict__ dinv,
                                                const float* __restrict__ bias, const float* __restrict__ rw,
                                                const float* __restrict__ rb, float* __restrict__ o8) {
  __shared__ float wl[128 * 8];
  int t = threadIdx.x;
  for (int i = t; i < 1024; i += 256) wl[i] = rw[i];
  __syncthreads();
  unsigned lane = t & 63u;
  int n = blockIdx.x * 4 + (t >> 6);
  float di = dinv[n];
  float2 self = __half22float2(h[((unsigned)n << 6) + lane]);
  float sx = 0.f, sy = 0.f;
  int2 bd = bounds[n];
  int p = __builtin_amdgcn_readfirstlane(bd.x);
  int p1 = __builtin_amdgcn_readfirstlane(bd.y);
  for (; p + 16 <= p1; p += 16) {
    unsigned c[16];
#pragma unroll
    for (int u = 0; u < 16; ++u) c[u] = csr[p + u];
    float2 f[16];
#pragma unroll
    for (int u = 0; u < 16; ++u) f[u] = __half22float2(h[((c[u] & 0xFFFFu) << 6) + lane]);
#pragma unroll
    for (int u = 0; u < 16; ++u) {
      float w = __half2float(__ushort_as_half((unsigned short)(c[u] >> 16)));
      sx += w * f[u].x;
      sy += w * f[u].y;
    }
  }
  for (; p + 4 <= p1; p += 4) {
    unsigned c[4];
#pragma unroll
    for (int u = 0; u < 4; ++u) c[u] = csr[p + u];
    float2 f[4];
#pragma unroll
    for (int u = 0; u < 4; ++u) f[u] = __half22float2(h[((c[u] & 0xFFFFu) << 6) + lane]);
#pragma unroll
    for (int u = 0; u < 4; ++u) {
      float w = __half2float(__ushort_as_half((unsigned short)(c[u] >> 16)));
      sx += w * f[u].x;
      sy += w * f[u].y;
    }
  }
  for (; p < p1; ++p) {
    unsigned c0 = csr[p];
    float2 f0 = __half22float2(h[((c0 & 0xFFFFu) << 6) + lane]);
    float w = __half2float(__ushort_as_half((unsigned short)(c0 >> 16)));
    sx += w * f0.x;
    sy += w * f0.y;
  }
  float2 bb = ((const float2*)bias)[lane];
  float m0 = mish_f(di * (sx + self.x) + bb.x);
  float m1 = mish_f(di * (sy + self.y) + bb.y);
  float p8[8];
#pragma unroll
  for (int k = 0; k < 8; ++k)
    p8[k] = m0 * wl[(2 * lane) * 8 + k] + m1 * wl[(2 * lane + 1) * 8 + k];
#pragma unroll
  for (int off = 1; off < 64; off <<= 1)
#pragma unroll
    for (int k = 0; k < 8; ++k) p8[k] += __shfl_xor(p8[k], off);
  if (lane < 8) o8[(size_t)n * 8 + lane] = mish_f(p8[lane] + rb[lane]);
}

// ---- fc1 split-K: z += feats[g, kc:kc+128] @ w[kc:kc+128, :] -------------
// fc1 bias omitted: BatchNorm (training mode) is invariant to a per-feature
// constant added to z (it shifts mu equally).
__global__ __launch_bounds__(448) void k_fc1(const float* __restrict__ feats, const float* __restrict__ w,
                                             float* __restrict__ z) {
  __shared__ float fs[8][128];
  int t = threadIdx.x;
  int kc = blockIdx.x * 128;
  int g0 = blockIdx.y * 8;
  for (int i = t; i < 1024; i += 448) {
    int g = i >> 7, k = i & 127;
    fs[g][k] = feats[(size_t)(g0 + g) * 3200 + kc + k];
  }
  __syncthreads();
  if (t < 400) {
    float a[8];
#pragma unroll
    for (int g = 0; g < 8; ++g) a[g] = 0.0f;
    for (int k = 0; k < 128; ++k) {
      float wv = w[(size_t)(kc + k) * 400 + t];
#pragma unroll
      for (int g = 0; g < 8; ++g) a[g] += fs[g][k] * wv;
    }
#pragma unroll
    for (int g = 0; g < 8; ++g) atomicAdd(&z[(size_t)(g0 + g) * 400 + t], a[g]);
  }
}

// ---- batchnorm stats: one block per feature, thread = batch element ------
__global__ __launch_bounds__(128) void k_bn(const float* __restrict__ z, const float* __restrict__ gamma,
                                            const float* __restrict__ beta, float* __restrict__ gs,
                                            float* __restrict__ gb) {
  int j = blockIdx.x;
  int b = threadIdx.x;
  float v = z[b * 400 + j];
  float s = v, s2 = v * v;
#pragma unroll
  for (int off = 1; off < 64; off <<= 1) {
    s += __shfl_xor(s, off);
    s2 += __shfl_xor(s2, off);
  }
  __shared__ float ls[2], ls2[2];
  if ((b & 63) == 0) {
    ls[b >> 6] = s;
    ls2[b >> 6] = s2;
  }
  __syncthreads();
  if (b == 0) {
    float mu = (ls[0] + ls[1]) * (1.0f / 128.0f);
    float var = (ls2[0] + ls2[1]) * (1.0f / 128.0f) - mu * mu;
    float rs = rsqrtf(var + 1e-5f);
    float g = gamma[j] * rs;
    gs[j] = g;
    gb[j] = beta[j] - mu * g;
  }
}

// ---- fc2: one block per graph, block-reduce over j -----------------------
__global__ __launch_bounds__(256) void k_fc2(const float* __restrict__ z, const float* __restrict__ gs,
                                             const float* __restrict__ gb, const float* __restrict__ w2,
                                             const float* __restrict__ b2, float* __restrict__ out) {
  int bg = blockIdx.x;
  int t = threadIdx.x;
  float a0 = 0.f, a1 = 0.f;
  for (int j = t; j < 400; j += 256) {
    float zn = z[bg * 400 + j] * gs[j] + gb[j];
    float m = mish_f(zn);
    a0 += m * w2[j * 2];
    a1 += m * w2[j * 2 + 1];
  }
#pragma unroll
  for (int off = 1; off < 64; off <<= 1) {
    a0 += __shfl_xor(a0, off);
    a1 += __shfl_xor(a1, off);
  }
  __shared__ float s0[4], s1[4];
  if ((t & 63) == 0) {
    s0[t >> 6] = a0;
    s1[t >> 6] = a1;
  }
  __syncthreads();
  if (t == 0) {
    out[bg * 2 + 0] = b2[0] + s0[0] + s0[1] + s0[2] + s0[3];
    out[bg * 2 + 1] = b2[1] + s1[0] + s1[1] + s1[2] + s1[3];
  }
}

extern "C" void kernel_launch(void* const* d_in, const int* in_sizes, int n_in,
                              void* d_out, int out_size, void* d_ws, size_t ws_size,
                              hipStream_t stream) {
  (void)in_sizes; (void)n_in; (void)out_size; (void)ws_size;
  const float* x   = (const float*)d_in[0];
  const int*   ei  = (const int*)d_in[1];
  const float* ew  = (const float*)d_in[2];
  const float* c1w = (const float*)d_in[4];
  const float* c1b = (const float*)d_in[5];
  const float* c2w = (const float*)d_in[6];
  const float* c2b = (const float*)d_in[7];
  const float* rw  = (const float*)d_in[8];
  const float* rb  = (const float*)d_in[9];
  const float* f1w = (const float*)d_in[10];
  const float* bng = (const float*)d_in[12];
  const float* bnb = (const float*)d_in[13];
  const float* f2w = (const float*)d_in[14];
  const float* f2b = (const float*)d_in[15];
  float* out = (float*)d_out;

  char* ws = (char*)d_ws;
  size_t off = 0;
  auto alloc = [&](size_t bytes) {
    void* p = ws + off;
    off = (off + bytes + 255) & ~(size_t)255;
    return p;
  };
  float* dinv    = (float*)alloc((size_t)NN * 4);
  int2*  bounds  = (int2*)alloc((size_t)NN * 8);
  unsigned* G    = (unsigned*)alloc((size_t)NBKT * NB * 4);  // 800 KB
  unsigned* btot = (unsigned*)alloc(NBKT * 4);
  unsigned* csr  = (unsigned*)alloc((size_t)NBKT * ECAP * 4);  // 9.8 MB packed
  __half* A1     = (__half*)alloc((size_t)NN * F * 2);       // gemm out (fp16, dinv-scaled)
  __half* B1     = (__half*)alloc((size_t)NN * F * 2);       // agg1 out (fp16)
  _Float16* Wt1  = (_Float16*)alloc((size_t)400 * 128 * 2);
  _Float16* Wt2  = (_Float16*)alloc((size_t)128 * 128 * 2);
  float* o8      = (float*)alloc((size_t)NN * 8 * 4);
  float* z       = (float*)alloc((size_t)128 * 400 * 4);
  float* gs      = (float*)alloc(400 * 4);
  float* gb      = (float*)alloc(400 * 4);

  // E (19.7 MB = NBKT*ECAP*8) aliases A1+B1 (26.2 MB contiguous): E's last
  // reader (k_fprep) completes before gemm1 writes A1 (stream-ordered).
  uint2* E = (uint2*)A1;

  // 11 dispatches total.
  k_ic<<<NB + 264, 256, 0, stream>>>(ei, G, c1w, c2w, Wt1, Wt2, z);
  k_bscan<<<NBKT, 64, 0, stream>>>(G, btot);
  k_cscat<<<NB, 256, 0, stream>>>(ei, ew, G, E);
  k_fprep<<<NBKT, 512, 0, stream>>>(E, btot, bounds, dinv, csr);

  // conv1: h" = dinv*(x@W1) (MFMA) ; agg+bias+mish
  k_gemm16<true><<<NN / 128, 256, 0, stream>>>(x, Wt1, dinv, A1, 400);
  k_agg<<<NN / 4, 256, 0, stream>>>((const __half2*)A1, bounds, csr, dinv, c1b, (__half2*)B1);
  // conv2 + fused readout -> o8 (feats)
  k_gemm16<false><<<NN / 128, 256, 0, stream>>>(B1, Wt2, dinv, A1, 128);
  k_agg2ro<<<NN / 4, 256, 0, stream>>>((const __half2*)A1, bounds, csr, dinv, c2b, rw, rb, o8);

  {
    dim3 g(25, 16);
    k_fc1<<<g, 448, 0, stream>>>(o8, f1w, z);
  }
  k_bn<<<400, 128, 0, stream>>>(z, bng, bnb, gs, gb);
  k_fc2<<<128, 256, 0, stream>>>(z, gs, gb, f2w, f2b, out);
}

// Round 10
// 405.867 us; speedup vs baseline: 1.5695x; 1.0089x over previous
//
#include <hip/hip_runtime.h>
#include <hip/hip_fp16.h>
#include <math.h>

#define NN 51200
#define NE 2048000
#define F 128
#define NB 1000        // sort blocks
#define EPB 2048       // edges per sort block (NB*EPB == NE)
#define NBKT 200       // buckets (dst >> 8)
#define ECAP 12288     // per-bucket edge capacity (mean 10240, max dev ~20 sigma)

typedef _Float16 half8 __attribute__((ext_vector_type(8)));
typedef float floatx4 __attribute__((ext_vector_type(4)));

__device__ __forceinline__ float mish_f(float x) {
  if (x > 20.0f) return x;
  float e = __expf(x);
  float w = 1.0f + e;
  w = w * w;
  return x * (w - 1.0f) / (w + 1.0f);
}

// ---- k_icsort: blocks 0..999: LDS-cached bucket sort of the edge list ----
//   (hist -> one global atomicAdd per (block,bucket) to claim space at the
//    static base b*ECAP -> scatter from LDS). Replaces chist+bscan+cscat;
//   within-bucket order is arbitrary (fprep handles any order).
// blocks 1000..1263: W1/W2 transpose to fp16 + zero z.
__global__ __launch_bounds__(256) void k_icsort(const int* __restrict__ ei, const float* __restrict__ ew,
                                                unsigned* __restrict__ gcnt, uint2* __restrict__ E,
                                                const float* __restrict__ W1, const float* __restrict__ W2,
                                                _Float16* __restrict__ Wt1, _Float16* __restrict__ Wt2,
                                                float* __restrict__ z) {
  int bid = blockIdx.x, t = threadIdx.x;
  if (bid < NB) {
    __shared__ uint2 ebuf[EPB];            // 16 KB: packed (src|dstLow, w)
    __shared__ unsigned char bkt[EPB];     // 2 KB
    __shared__ unsigned hist[NBKT];
    __shared__ unsigned base[NBKT];
    for (int i = t; i < NBKT; i += 256) hist[i] = 0u;
    __syncthreads();
    int off0 = bid * EPB;
    for (int it = 0; it < EPB; it += 256) {
      int e = off0 + it + t;
      int dst = ei[NE + e];
      int src = ei[e];
      float w = ew[e];
      ebuf[it + t] = make_uint2((unsigned)src | ((unsigned)(dst & 255) << 16), __float_as_uint(w));
      int b = dst >> 8;
      bkt[it + t] = (unsigned char)b;
      atomicAdd(&hist[b], 1u);
    }
    __syncthreads();
    for (int i = t; i < NBKT; i += 256)
      base[i] = (unsigned)i * ECAP + atomicAdd(&gcnt[i], hist[i]);
    __syncthreads();
    for (int it = 0; it < EPB; it += 256) {
      int j = it + t;
      unsigned b = bkt[j];
      unsigned pos = atomicAdd(&base[b], 1u);
      E[pos] = ebuf[j];
    }
  } else {
    int idx = (bid - NB) * 256 + t;  // 0..67583 = 51200 (W1) + 16384 (W2)
    if (idx < 51200) {
      int k = idx >> 7, n = idx & 127;
      Wt1[n * 400 + k] = (_Float16)W1[idx];
      z[idx] = 0.0f;  // z is 128*400 == 51200 floats
    } else {
      int i2 = idx - 51200;
      int k = i2 >> 7, n = i2 & 127;
      Wt2[n * 128 + k] = (_Float16)W2[i2];
    }
  }
}

// ---- k_fprep: per-bucket count+degsum -> LDS scan -> bounds/dinv -> scatter
// csr entry packed 4B: src (16b) | fp16(ew) << 16 (dinv folded into the gemm
// epilogue row-scale). Plain stores (L2-coalescing); 512 thr halves E-pass
// latency. gcnt (from k_icsort) is the per-bucket total.
__global__ __launch_bounds__(512) void k_fprep(const uint2* __restrict__ E, const unsigned* __restrict__ btot,
                                               int2* __restrict__ bounds, float* __restrict__ dinv,
                                               unsigned* __restrict__ csr) {
  __shared__ unsigned lc[256];
  __shared__ float ld[256];
  __shared__ int curs[256];
  __shared__ int ws4[4];
  int b = blockIdx.x, t = threadIdx.x;
  if (t < 256) {
    lc[t] = 0u;
    ld[t] = 0.f;
  }
  __syncthreads();
  unsigned e0 = (unsigned)b * ECAP, e1 = e0 + btot[b];
  for (unsigned e = e0 + t; e < e1; e += 512) {
    uint2 v = E[e];
    unsigned node = (v.x >> 16) & 255u;
    atomicAdd(&lc[node], 1u);
    atomicAdd(&ld[node], __uint_as_float(v.y));
  }
  __syncthreads();
  if (t < 256) {
    int lane = t & 63, wid = t >> 6;
    int cv = (int)lc[t];
    int x = cv;
#pragma unroll
    for (int off = 1; off < 64; off <<= 1) {
      int y = __shfl_up(x, off);
      if (lane >= off) x += y;
    }
    if (lane == 63) ws4[wid] = x;
    __syncthreads();
    int woff = 0;
    for (int k = 0; k < wid; ++k) woff += ws4[k];
    int start = (int)e0 + woff + x - cv;
    bounds[b * 256 + t] = make_int2(start, start + cv);
    dinv[b * 256 + t] = rsqrtf(ld[t] + 1.0f);  // +1 = self-loop weight
    curs[t] = start;
  } else {
    __syncthreads();
  }
  __syncthreads();
  for (unsigned e = e0 + t; e < e1; e += 512) {
    uint2 v = E[e];
    unsigned node = (v.x >> 16) & 255u;
    unsigned src = v.x & 0xFFFFu;
    int p = atomicAdd(&curs[node], 1);
    unsigned pk = src | ((unsigned)__half_as_ushort(__float2half_rn(__uint_as_float(v.y))) << 16);
    csr[p] = pk;
  }
}

// ---- MFMA GEMM with dinv row-scale epilogue: C[r] = fp16(dinv[r]*(A@W)[r])
template <bool A_IS_F32>
__global__ __launch_bounds__(256) void k_gemm16(const void* __restrict__ Av,
                                                const _Float16* __restrict__ Wt,
                                                const float* __restrict__ dinv,
                                                __half* __restrict__ C, int K) {
  __shared__ _Float16 As[128][40];
  __shared__ _Float16 Bs[128][40];
  int t = threadIdx.x;
  int bm = blockIdx.x * 128;
  int w = t >> 6, l = t & 63, rr = l & 15, q = l >> 4;
  int si = t >> 1, sj = (t & 1) * 16;

  floatx4 acc[2][8];
#pragma unroll
  for (int a = 0; a < 2; ++a)
#pragma unroll
    for (int b = 0; b < 8; ++b) acc[a][b] = (floatx4){0.f, 0.f, 0.f, 0.f};

  for (int k0 = 0; k0 < K; k0 += 32) {
    if (A_IS_F32) {
      const float* A = (const float*)Av;
      half8 h0, h1;
      if (k0 + sj < K) {
        const float* ap = A + (size_t)(bm + si) * K + k0 + sj;
        float4 v0 = *(const float4*)(ap + 0);
        float4 v1 = *(const float4*)(ap + 4);
        float4 v2 = *(const float4*)(ap + 8);
        float4 v3 = *(const float4*)(ap + 12);
        h0 = (half8){(_Float16)v0.x, (_Float16)v0.y, (_Float16)v0.z, (_Float16)v0.w,
                     (_Float16)v1.x, (_Float16)v1.y, (_Float16)v1.z, (_Float16)v1.w};
        h1 = (half8){(_Float16)v2.x, (_Float16)v2.y, (_Float16)v2.z, (_Float16)v2.w,
                     (_Float16)v3.x, (_Float16)v3.y, (_Float16)v3.z, (_Float16)v3.w};
      } else {
        h0 = (half8){0, 0, 0, 0, 0, 0, 0, 0};
        h1 = h0;
      }
      *(half8*)&As[si][sj] = h0;
      *(half8*)&As[si][sj + 8] = h1;
    } else {
      const __half* A = (const __half*)Av;
      uint4 u0, u1;
      if (k0 + sj < K) {
        const __half* ap = A + (size_t)(bm + si) * K + k0 + sj;
        u0 = *(const uint4*)ap;
        u1 = *(const uint4*)(ap + 8);
      } else {
        u0 = make_uint4(0, 0, 0, 0);
        u1 = u0;
      }
      *(uint4*)&As[si][sj] = u0;
      *(uint4*)&As[si][sj + 8] = u1;
    }
    {
      uint4 u0, u1;
      if (k0 + sj < K) {
        const _Float16* wp = Wt + (size_t)si * K + k0 + sj;
        u0 = *(const uint4*)wp;
        u1 = *(const uint4*)(wp + 8);
      } else {
        u0 = make_uint4(0, 0, 0, 0);
        u1 = u0;
      }
      *(uint4*)&Bs[si][sj] = u0;
      *(uint4*)&Bs[si][sj + 8] = u1;
    }
    __syncthreads();

    half8 a0 = *(const half8*)&As[w * 32 + rr][q * 8];
    half8 a1 = *(const half8*)&As[w * 32 + 16 + rr][q * 8];
#pragma unroll
    for (int nt = 0; nt < 8; ++nt) {
      half8 b = *(const half8*)&Bs[nt * 16 + rr][q * 8];
      acc[0][nt] = __builtin_amdgcn_mfma_f32_16x16x32_f16(a0, b, acc[0][nt], 0, 0, 0);
      acc[1][nt] = __builtin_amdgcn_mfma_f32_16x16x32_f16(a1, b, acc[1][nt], 0, 0, 0);
    }
    __syncthreads();
  }
#pragma unroll
  for (int mt = 0; mt < 2; ++mt) {
    float dv[4];
#pragma unroll
    for (int r4 = 0; r4 < 4; ++r4) dv[r4] = dinv[bm + w * 32 + mt * 16 + q * 4 + r4];
#pragma unroll
    for (int nt = 0; nt < 8; ++nt)
#pragma unroll
      for (int r4 = 0; r4 < 4; ++r4) {
        int row = bm + w * 32 + mt * 16 + q * 4 + r4;
        C[(size_t)row * 128 + nt * 16 + rr] = __float2half(dv[r4] * acc[mt][nt][r4]);
      }
  }
}

// ---- conv1 agg: out[n] = mish(di*(sum ew*h"[src] + h"[n]) + bias) --------
__global__ __launch_bounds__(256) void k_agg(const __half2* __restrict__ h, const int2* __restrict__ bounds,
                                             const unsigned* __restrict__ csr, const float* __restrict__ dinv,
                                             const float* __restrict__ bias, __half2* __restrict__ out) {
  unsigned lane = threadIdx.x & 63u;
  int n = blockIdx.x * 4 + (threadIdx.x >> 6);
  float di = dinv[n];
  float2 self = __half22float2(h[((unsigned)n << 6) + lane]);
  float sx = 0.f, sy = 0.f;
  int2 bd = bounds[n];
  int p = __builtin_amdgcn_readfirstlane(bd.x);
  int p1 = __builtin_amdgcn_readfirstlane(bd.y);
  for (; p + 16 <= p1; p += 16) {
    unsigned c[16];
#pragma unroll
    for (int u = 0; u < 16; ++u) c[u] = csr[p + u];
    float2 f[16];
#pragma unroll
    for (int u = 0; u < 16; ++u) f[u] = __half22float2(h[((c[u] & 0xFFFFu) << 6) + lane]);
#pragma unroll
    for (int u = 0; u < 16; ++u) {
      float w = __half2float(__ushort_as_half((unsigned short)(c[u] >> 16)));
      sx += w * f[u].x;
      sy += w * f[u].y;
    }
  }
  for (; p + 4 <= p1; p += 4) {
    unsigned c[4];
#pragma unroll
    for (int u = 0; u < 4; ++u) c[u] = csr[p + u];
    float2 f[4];
#pragma unroll
    for (int u = 0; u < 4; ++u) f[u] = __half22float2(h[((c[u] & 0xFFFFu) << 6) + lane]);
#pragma unroll
    for (int u = 0; u < 4; ++u) {
      float w = __half2float(__ushort_as_half((unsigned short)(c[u] >> 16)));
      sx += w * f[u].x;
      sy += w * f[u].y;
    }
  }
  for (; p < p1; ++p) {
    unsigned c0 = csr[p];
    float2 f0 = __half22float2(h[((c0 & 0xFFFFu) << 6) + lane]);
    float w = __half2float(__ushort_as_half((unsigned short)(c0 >> 16)));
    sx += w * f0.x;
    sy += w * f0.y;
  }
  float2 bb = ((const float2*)bias)[lane];
  float ax = di * (sx + self.x) + bb.x;
  float ay = di * (sy + self.y) + bb.y;
  out[((unsigned)n << 6) + lane] = __floats2half2_rn(mish_f(ax), mish_f(ay));
}

// ---- conv2 agg FUSED with readout: o8[n][k] directly ---------------------
// Readout weights in LDS transposed as float2 wl2[8][64] (2-way bank alias,
// free). Reduce: FULL xor butterfly (all 64 lanes must be summed for every
// k -- the shfl_down(32/16/8) tree only summed lanes == l mod 8, round-9 bug).
__global__ __launch_bounds__(256) void k_agg2ro(const __half2* __restrict__ h, const int2* __restrict__ bounds,
                                                const unsigned* __restrict__ csr, const float* __restrict__ dinv,
                                                const float* __restrict__ bias, const float* __restrict__ rw,
                                                const float* __restrict__ rb, float* __restrict__ o8) {
  __shared__ float2 wl2[8][64];
  int t = threadIdx.x;
  for (int i = t; i < 512; i += 256) {
    int k = i >> 6, l = i & 63;
    wl2[k][l] = make_float2(rw[(2 * l) * 8 + k], rw[(2 * l + 1) * 8 + k]);
  }
  __syncthreads();
  unsigned lane = t & 63u;
  int n = blockIdx.x * 4 + (t >> 6);
  float di = dinv[n];
  float2 self = __half22float2(h[((unsigned)n << 6) + lane]);
  float sx = 0.f, sy = 0.f;
  int2 bd = bounds[n];
  int p = __builtin_amdgcn_readfirstlane(bd.x);
  int p1 = __builtin_amdgcn_readfirstlane(bd.y);
  for (; p + 16 <= p1; p += 16) {
    unsigned c[16];
#pragma unroll
    for (int u = 0; u < 16; ++u) c[u] = csr[p + u];
    float2 f[16];
#pragma unroll
    for (int u = 0; u < 16; ++u) f[u] = __half22float2(h[((c[u] & 0xFFFFu) << 6) + lane]);
#pragma unroll
    for (int u = 0; u < 16; ++u) {
      float w = __half2float(__ushort_as_half((unsigned short)(c[u] >> 16)));
      sx += w * f[u].x;
      sy += w * f[u].y;
    }
  }
  for (; p + 4 <= p1; p += 4) {
    unsigned c[4];
#pragma unroll
    for (int u = 0; u < 4; ++u) c[u] = csr[p + u];
    float2 f[4];
#pragma unroll
    for (int u = 0; u < 4; ++u) f[u] = __half22float2(h[((c[u] & 0xFFFFu) << 6) + lane]);
#pragma unroll
    for (int u = 0; u < 4; ++u) {
      float w = __half2float(__ushort_as_half((unsigned short)(c[u] >> 16)));
      sx += w * f[u].x;
      sy += w * f[u].y;
    }
  }
  for (; p < p1; ++p) {
    unsigned c0 = csr[p];
    float2 f0 = __half22float2(h[((c0 & 0xFFFFu) << 6) + lane]);
    float w = __half2float(__ushort_as_half((unsigned short)(c0 >> 16)));
    sx += w * f0.x;
    sy += w * f0.y;
  }
  float2 bb = ((const float2*)bias)[lane];
  float m0 = mish_f(di * (sx + self.x) + bb.x);
  float m1 = mish_f(di * (sy + self.y) + bb.y);
  float p8[8];
#pragma unroll
  for (int k = 0; k < 8; ++k) {
    float2 wv = wl2[k][lane];
    p8[k] = m0 * wv.x + m1 * wv.y;
  }
#pragma unroll
  for (int off = 1; off < 64; off <<= 1)
#pragma unroll
    for (int k = 0; k < 8; ++k) p8[k] += __shfl_xor(p8[k], off);
  if (lane < 8) o8[(size_t)n * 8 + lane] = mish_f(p8[lane] + rb[lane]);
}

// ---- fc1 split-K: z += feats[g, kc:kc+128] @ w[kc:kc+128, :] -------------
// fc1 bias omitted: BatchNorm (training mode) is invariant to a per-feature
// constant added to z (it shifts mu equally).
__global__ __launch_bounds__(448) void k_fc1(const float* __restrict__ feats, const float* __restrict__ w,
                                             float* __restrict__ z) {
  __shared__ float fs[8][128];
  int t = threadIdx.x;
  int kc = blockIdx.x * 128;
  int g0 = blockIdx.y * 8;
  for (int i = t; i < 1024; i += 448) {
    int g = i >> 7, k = i & 127;
    fs[g][k] = feats[(size_t)(g0 + g) * 3200 + kc + k];
  }
  __syncthreads();
  if (t < 400) {
    float a[8];
#pragma unroll
    for (int g = 0; g < 8; ++g) a[g] = 0.0f;
    for (int k = 0; k < 128; ++k) {
      float wv = w[(size_t)(kc + k) * 400 + t];
#pragma unroll
      for (int g = 0; g < 8; ++g) a[g] += fs[g][k] * wv;
    }
#pragma unroll
    for (int g = 0; g < 8; ++g) atomicAdd(&z[(size_t)(g0 + g) * 400 + t], a[g]);
  }
}

// ---- batchnorm stats: one block per feature, thread = batch element ------
__global__ __launch_bounds__(128) void k_bn(const float* __restrict__ z, const float* __restrict__ gamma,
                                            const float* __restrict__ beta, float* __restrict__ gs,
                                            float* __restrict__ gb) {
  int j = blockIdx.x;
  int b = threadIdx.x;
  float v = z[b * 400 + j];
  float s = v, s2 = v * v;
#pragma unroll
  for (int off = 1; off < 64; off <<= 1) {
    s += __shfl_xor(s, off);
    s2 += __shfl_xor(s2, off);
  }
  __shared__ float ls[2], ls2[2];
  if ((b & 63) == 0) {
    ls[b >> 6] = s;
    ls2[b >> 6] = s2;
  }
  __syncthreads();
  if (b == 0) {
    float mu = (ls[0] + ls[1]) * (1.0f / 128.0f);
    float var = (ls2[0] + ls2[1]) * (1.0f / 128.0f) - mu * mu;
    float rs = rsqrtf(var + 1e-5f);
    float g = gamma[j] * rs;
    gs[j] = g;
    gb[j] = beta[j] - mu * g;
  }
}

// ---- fc2: one block per graph, block-reduce over j -----------------------
__global__ __launch_bounds__(256) void k_fc2(const float* __restrict__ z, const float* __restrict__ gs,
                                             const float* __restrict__ gb, const float* __restrict__ w2,
                                             const float* __restrict__ b2, float* __restrict__ out) {
  int bg = blockIdx.x;
  int t = threadIdx.x;
  float a0 = 0.f, a1 = 0.f;
  for (int j = t; j < 400; j += 256) {
    float zn = z[bg * 400 + j] * gs[j] + gb[j];
    float m = mish_f(zn);
    a0 += m * w2[j * 2];
    a1 += m * w2[j * 2 + 1];
  }
#pragma unroll
  for (int off = 1; off < 64; off <<= 1) {
    a0 += __shfl_xor(a0, off);
    a1 += __shfl_xor(a1, off);
  }
  __shared__ float s0[4], s1[4];
  if ((t & 63) == 0) {
    s0[t >> 6] = a0;
    s1[t >> 6] = a1;
  }
  __syncthreads();
  if (t == 0) {
    out[bg * 2 + 0] = b2[0] + s0[0] + s0[1] + s0[2] + s0[3];
    out[bg * 2 + 1] = b2[1] + s1[0] + s1[1] + s1[2] + s1[3];
  }
}

extern "C" void kernel_launch(void* const* d_in, const int* in_sizes, int n_in,
                              void* d_out, int out_size, void* d_ws, size_t ws_size,
                              hipStream_t stream) {
  (void)in_sizes; (void)n_in; (void)out_size; (void)ws_size;
  const float* x   = (const float*)d_in[0];
  const int*   ei  = (const int*)d_in[1];
  const float* ew  = (const float*)d_in[2];
  const float* c1w = (const float*)d_in[4];
  const float* c1b = (const float*)d_in[5];
  const float* c2w = (const float*)d_in[6];
  const float* c2b = (const float*)d_in[7];
  const float* rw  = (const float*)d_in[8];
  const float* rb  = (const float*)d_in[9];
  const float* f1w = (const float*)d_in[10];
  const float* bng = (const float*)d_in[12];
  const float* bnb = (const float*)d_in[13];
  const float* f2w = (const float*)d_in[14];
  const float* f2b = (const float*)d_in[15];
  float* out = (float*)d_out;

  char* ws = (char*)d_ws;
  size_t off = 0;
  auto alloc = [&](size_t bytes) {
    void* p = ws + off;
    off = (off + bytes + 255) & ~(size_t)255;
    return p;
  };
  float* dinv    = (float*)alloc((size_t)NN * 4);
  int2*  bounds  = (int2*)alloc((size_t)NN * 8);
  unsigned* gcnt = (unsigned*)alloc(NBKT * 4);               // bucket totals (zeroed by memset)
  unsigned* csr  = (unsigned*)alloc((size_t)NBKT * ECAP * 4);  // 9.8 MB packed
  __half* A1     = (__half*)alloc((size_t)NN * F * 2);       // gemm out (fp16, dinv-scaled)
  __half* B1     = (__half*)alloc((size_t)NN * F * 2);       // agg1 out (fp16)
  _Float16* Wt1  = (_Float16*)alloc((size_t)400 * 128 * 2);
  _Float16* Wt2  = (_Float16*)alloc((size_t)128 * 128 * 2);
  float* o8      = (float*)alloc((size_t)NN * 8 * 4);
  float* z       = (float*)alloc((size_t)128 * 400 * 4);
  float* gs      = (float*)alloc(400 * 4);
  float* gb      = (float*)alloc(400 * 4);

  // E (19.7 MB = NBKT*ECAP*8) aliases A1+B1 (26.2 MB contiguous): E's last
  // reader (k_fprep) completes before gemm1 writes A1 (stream-ordered).
  uint2* E = (uint2*)A1;

  // 9 kernels + 1 tiny memset.
  hipMemsetAsync(gcnt, 0, NBKT * 4, stream);
  k_icsort<<<NB + 264, 256, 0, stream>>>(ei, ew, gcnt, E, c1w, c2w, Wt1, Wt2, z);
  k_fprep<<<NBKT, 512, 0, stream>>>(E, gcnt, bounds, dinv, csr);

  // conv1: h" = dinv*(x@W1) (MFMA) ; agg+bias+mish
  k_gemm16<true><<<NN / 128, 256, 0, stream>>>(x, Wt1, dinv, A1, 400);
  k_agg<<<NN / 4, 256, 0, stream>>>((const __half2*)A1, bounds, csr, dinv, c1b, (__half2*)B1);
  // conv2 + fused readout -> o8 (feats)
  k_gemm16<false><<<NN / 128, 256, 0, stream>>>(B1, Wt2, dinv, A1, 128);
  k_agg2ro<<<NN / 4, 256, 0, stream>>>((const __half2*)A1, bounds, csr, dinv, c2b, rw, rb, o8);

  {
    dim3 g(25, 16);
    k_fc1<<<g, 448, 0, stream>>>(o8, f1w, z);
  }
  k_bn<<<400, 128, 0, stream>>>(z, bng, bnb, gs, gb);
  k_fc2<<<128, 256, 0, stream>>>(z, gs, gb, f2w, f2b, out);
}

// Round 11
// 401.686 us; speedup vs baseline: 1.5859x; 1.0104x over previous
//
#include <hip/hip_runtime.h>
#include <hip/hip_fp16.h>
#include <math.h>

#define NN 51200
#define NE 2048000
#define F 128
#define NB 1000        // sort blocks
#define EPB 2048       // edges per sort block (NB*EPB == NE)
#define NBKT 200       // buckets (dst >> 8)
#define ECAP 12288     // per-bucket edge capacity (mean 10240, max dev ~20 sigma)

typedef _Float16 half8 __attribute__((ext_vector_type(8)));
typedef float floatx4 __attribute__((ext_vector_type(4)));

__device__ __forceinline__ float mish_f(float x) {
  if (x > 20.0f) return x;
  float e = __expf(x);
  float w = 1.0f + e;
  w = w * w;
  return x * (w - 1.0f) / (w + 1.0f);
}

// ---- k_icsort: blocks 0..999: LDS-cached bucket sort of the edge list ----
// blocks 1000..1263: W1/W2 transpose to fp16 + zero z.
__global__ __launch_bounds__(256) void k_icsort(const int* __restrict__ ei, const float* __restrict__ ew,
                                                unsigned* __restrict__ gcnt, uint2* __restrict__ E,
                                                const float* __restrict__ W1, const float* __restrict__ W2,
                                                _Float16* __restrict__ Wt1, _Float16* __restrict__ Wt2,
                                                float* __restrict__ z) {
  int bid = blockIdx.x, t = threadIdx.x;
  if (bid < NB) {
    __shared__ uint2 ebuf[EPB];            // 16 KB: packed (src|dstLow, w)
    __shared__ unsigned char bkt[EPB];     // 2 KB
    __shared__ unsigned hist[NBKT];
    __shared__ unsigned base[NBKT];
    for (int i = t; i < NBKT; i += 256) hist[i] = 0u;
    __syncthreads();
    int off0 = bid * EPB;
    for (int it = 0; it < EPB; it += 256) {
      int e = off0 + it + t;
      int dst = ei[NE + e];
      int src = ei[e];
      float w = ew[e];
      ebuf[it + t] = make_uint2((unsigned)src | ((unsigned)(dst & 255) << 16), __float_as_uint(w));
      int b = dst >> 8;
      bkt[it + t] = (unsigned char)b;
      atomicAdd(&hist[b], 1u);
    }
    __syncthreads();
    for (int i = t; i < NBKT; i += 256)
      base[i] = (unsigned)i * ECAP + atomicAdd(&gcnt[i], hist[i]);
    __syncthreads();
    for (int it = 0; it < EPB; it += 256) {
      int j = it + t;
      unsigned b = bkt[j];
      unsigned pos = atomicAdd(&base[b], 1u);
      E[pos] = ebuf[j];
    }
  } else {
    int idx = (bid - NB) * 256 + t;  // 0..67583 = 51200 (W1) + 16384 (W2)
    if (idx < 51200) {
      int k = idx >> 7, n = idx & 127;
      Wt1[n * 400 + k] = (_Float16)W1[idx];
      z[idx] = 0.0f;  // z is 128*400 == 51200 floats
    } else {
      int i2 = idx - 51200;
      int k = i2 >> 7, n = i2 & 127;
      Wt2[n * 128 + k] = (_Float16)W2[i2];
    }
  }
}

// ---- k_fprep: per-bucket count+degsum -> LDS scan -> bounds/dinv -> scatter
// 1024 threads/block (was 512): the two serial E-passes over ~10K edges per
// bucket are latency chains; 2x threads halves both. Sync structure keeps
// __syncthreads outside divergent branches.
__global__ __launch_bounds__(1024) void k_fprep(const uint2* __restrict__ E, const unsigned* __restrict__ btot,
                                                int2* __restrict__ bounds, float* __restrict__ dinv,
                                                unsigned* __restrict__ csr) {
  __shared__ unsigned lc[256];
  __shared__ float ld[256];
  __shared__ int curs[256];
  __shared__ int ws4[4];
  int b = blockIdx.x, t = threadIdx.x;
  if (t < 256) {
    lc[t] = 0u;
    ld[t] = 0.f;
  }
  __syncthreads();
  unsigned e0 = (unsigned)b * ECAP, e1 = e0 + btot[b];
  for (unsigned e = e0 + t; e < e1; e += 1024) {
    uint2 v = E[e];
    unsigned node = (v.x >> 16) & 255u;
    atomicAdd(&lc[node], 1u);
    atomicAdd(&ld[node], __uint_as_float(v.y));
  }
  __syncthreads();
  // exclusive scan of lc[0..255]; waves >= 4 compute garbage, write nothing
  int lane = t & 63, wid = (t >> 6) & 3;
  int cv = (t < 256) ? (int)lc[t] : 0;
  int x = cv;
#pragma unroll
  for (int off = 1; off < 64; off <<= 1) {
    int y = __shfl_up(x, off);
    if (lane >= off) x += y;
  }
  if (t < 256 && lane == 63) ws4[wid] = x;
  __syncthreads();
  if (t < 256) {
    int woff = 0;
    for (int k = 0; k < wid; ++k) woff += ws4[k];
    int start = (int)e0 + woff + x - cv;
    bounds[b * 256 + t] = make_int2(start, start + cv);
    dinv[b * 256 + t] = rsqrtf(ld[t] + 1.0f);  // +1 = self-loop weight
    curs[t] = start;
  }
  __syncthreads();
  for (unsigned e = e0 + t; e < e1; e += 1024) {
    uint2 v = E[e];
    unsigned node = (v.x >> 16) & 255u;
    unsigned src = v.x & 0xFFFFu;
    int p = atomicAdd(&curs[node], 1);
    unsigned pk = src | ((unsigned)__half_as_ushort(__float2half_rn(__uint_as_float(v.y))) << 16);
    csr[p] = pk;
  }
}

// ---- MFMA GEMM with dinv row-scale epilogue: C[r] = fp16(dinv[r]*(A@W)[r])
template <bool A_IS_F32>
__global__ __launch_bounds__(256) void k_gemm16(const void* __restrict__ Av,
                                                const _Float16* __restrict__ Wt,
                                                const float* __restrict__ dinv,
                                                __half* __restrict__ C, int K) {
  __shared__ _Float16 As[128][40];
  __shared__ _Float16 Bs[128][40];
  int t = threadIdx.x;
  int bm = blockIdx.x * 128;
  int w = t >> 6, l = t & 63, rr = l & 15, q = l >> 4;
  int si = t >> 1, sj = (t & 1) * 16;

  floatx4 acc[2][8];
#pragma unroll
  for (int a = 0; a < 2; ++a)
#pragma unroll
    for (int b = 0; b < 8; ++b) acc[a][b] = (floatx4){0.f, 0.f, 0.f, 0.f};

  for (int k0 = 0; k0 < K; k0 += 32) {
    if (A_IS_F32) {
      const float* A = (const float*)Av;
      half8 h0, h1;
      if (k0 + sj < K) {
        const float* ap = A + (size_t)(bm + si) * K + k0 + sj;
        float4 v0 = *(const float4*)(ap + 0);
        float4 v1 = *(const float4*)(ap + 4);
        float4 v2 = *(const float4*)(ap + 8);
        float4 v3 = *(const float4*)(ap + 12);
        h0 = (half8){(_Float16)v0.x, (_Float16)v0.y, (_Float16)v0.z, (_Float16)v0.w,
                     (_Float16)v1.x, (_Float16)v1.y, (_Float16)v1.z, (_Float16)v1.w};
        h1 = (half8){(_Float16)v2.x, (_Float16)v2.y, (_Float16)v2.z, (_Float16)v2.w,
                     (_Float16)v3.x, (_Float16)v3.y, (_Float16)v3.z, (_Float16)v3.w};
      } else {
        h0 = (half8){0, 0, 0, 0, 0, 0, 0, 0};
        h1 = h0;
      }
      *(half8*)&As[si][sj] = h0;
      *(half8*)&As[si][sj + 8] = h1;
    } else {
      const __half* A = (const __half*)Av;
      uint4 u0, u1;
      if (k0 + sj < K) {
        const __half* ap = A + (size_t)(bm + si) * K + k0 + sj;
        u0 = *(const uint4*)ap;
        u1 = *(const uint4*)(ap + 8);
      } else {
        u0 = make_uint4(0, 0, 0, 0);
        u1 = u0;
      }
      *(uint4*)&As[si][sj] = u0;
      *(uint4*)&As[si][sj + 8] = u1;
    }
    {
      uint4 u0, u1;
      if (k0 + sj < K) {
        const _Float16* wp = Wt + (size_t)si * K + k0 + sj;
        u0 = *(const uint4*)wp;
        u1 = *(const uint4*)(wp + 8);
      } else {
        u0 = make_uint4(0, 0, 0, 0);
        u1 = u0;
      }
      *(uint4*)&Bs[si][sj] = u0;
      *(uint4*)&Bs[si][sj + 8] = u1;
    }
    __syncthreads();

    half8 a0 = *(const half8*)&As[w * 32 + rr][q * 8];
    half8 a1 = *(const half8*)&As[w * 32 + 16 + rr][q * 8];
#pragma unroll
    for (int nt = 0; nt < 8; ++nt) {
      half8 b = *(const half8*)&Bs[nt * 16 + rr][q * 8];
      acc[0][nt] = __builtin_amdgcn_mfma_f32_16x16x32_f16(a0, b, acc[0][nt], 0, 0, 0);
      acc[1][nt] = __builtin_amdgcn_mfma_f32_16x16x32_f16(a1, b, acc[1][nt], 0, 0, 0);
    }
    __syncthreads();
  }
#pragma unroll
  for (int mt = 0; mt < 2; ++mt) {
    float dv[4];
#pragma unroll
    for (int r4 = 0; r4 < 4; ++r4) dv[r4] = dinv[bm + w * 32 + mt * 16 + q * 4 + r4];
#pragma unroll
    for (int nt = 0; nt < 8; ++nt)
#pragma unroll
      for (int r4 = 0; r4 < 4; ++r4) {
        int row = bm + w * 32 + mt * 16 + q * 4 + r4;
        C[(size_t)row * 128 + nt * 16 + rr] = __float2half(dv[r4] * acc[mt][nt][r4]);
      }
  }
}

// ---- conv1 agg: out[n] = mish(di*(sum ew*h"[src] + h"[n]) + bias) --------
__global__ __launch_bounds__(256) void k_agg(const __half2* __restrict__ h, const int2* __restrict__ bounds,
                                             const unsigned* __restrict__ csr, const float* __restrict__ dinv,
                                             const float* __restrict__ bias, __half2* __restrict__ out) {
  unsigned lane = threadIdx.x & 63u;
  int n = blockIdx.x * 4 + (threadIdx.x >> 6);
  float di = dinv[n];
  float2 self = __half22float2(h[((unsigned)n << 6) + lane]);
  float sx = 0.f, sy = 0.f;
  int2 bd = bounds[n];
  int p = __builtin_amdgcn_readfirstlane(bd.x);
  int p1 = __builtin_amdgcn_readfirstlane(bd.y);
  for (; p + 16 <= p1; p += 16) {
    unsigned c[16];
#pragma unroll
    for (int u = 0; u < 16; ++u) c[u] = csr[p + u];
    float2 f[16];
#pragma unroll
    for (int u = 0; u < 16; ++u) f[u] = __half22float2(h[((c[u] & 0xFFFFu) << 6) + lane]);
#pragma unroll
    for (int u = 0; u < 16; ++u) {
      float w = __half2float(__ushort_as_half((unsigned short)(c[u] >> 16)));
      sx += w * f[u].x;
      sy += w * f[u].y;
    }
  }
  for (; p + 4 <= p1; p += 4) {
    unsigned c[4];
#pragma unroll
    for (int u = 0; u < 4; ++u) c[u] = csr[p + u];
    float2 f[4];
#pragma unroll
    for (int u = 0; u < 4; ++u) f[u] = __half22float2(h[((c[u] & 0xFFFFu) << 6) + lane]);
#pragma unroll
    for (int u = 0; u < 4; ++u) {
      float w = __half2float(__ushort_as_half((unsigned short)(c[u] >> 16)));
      sx += w * f[u].x;
      sy += w * f[u].y;
    }
  }
  for (; p < p1; ++p) {
    unsigned c0 = csr[p];
    float2 f0 = __half22float2(h[((c0 & 0xFFFFu) << 6) + lane]);
    float w = __half2float(__ushort_as_half((unsigned short)(c0 >> 16)));
    sx += w * f0.x;
    sy += w * f0.y;
  }
  float2 bb = ((const float2*)bias)[lane];
  float ax = di * (sx + self.x) + bb.x;
  float ay = di * (sy + self.y) + bb.y;
  out[((unsigned)n << 6) + lane] = __floats2half2_rn(mish_f(ax), mish_f(ay));
}

// ---- conv2 agg FUSED with readout: o8[n][k] directly ---------------------
// Readout reduce via REDUCE-SCATTER (10 shfl, was 48-shfl full butterfly):
// off=32 keeps 4 k-values (4 shfl), off=16 keeps 2 (2), off=8 keeps 1 (1),
// then intra-8 butterfly offs 1/2/4 (3). After the k-folding steps, lane l
// holds the sum over lanes {same l&7} for k=(l>>3) (xor over bits 5,4,3
// covers the 8 groups); the intra-8 butterfly (bits 0,1,2) completes all 64
// lanes. Lanes l&7==0 write k=(l>>3).
__global__ __launch_bounds__(256) void k_agg2ro(const __half2* __restrict__ h, const int2* __restrict__ bounds,
                                                const unsigned* __restrict__ csr, const float* __restrict__ dinv,
                                                const float* __restrict__ bias, const float* __restrict__ rw,
                                                const float* __restrict__ rb, float* __restrict__ o8) {
  __shared__ float2 wl2[8][64];
  int t = threadIdx.x;
  for (int i = t; i < 512; i += 256) {
    int k = i >> 6, l = i & 63;
    wl2[k][l] = make_float2(rw[(2 * l) * 8 + k], rw[(2 * l + 1) * 8 + k]);
  }
  __syncthreads();
  unsigned lane = t & 63u;
  int n = blockIdx.x * 4 + (t >> 6);
  float di = dinv[n];
  float2 self = __half22float2(h[((unsigned)n << 6) + lane]);
  float sx = 0.f, sy = 0.f;
  int2 bd = bounds[n];
  int p = __builtin_amdgcn_readfirstlane(bd.x);
  int p1 = __builtin_amdgcn_readfirstlane(bd.y);
  for (; p + 16 <= p1; p += 16) {
    unsigned c[16];
#pragma unroll
    for (int u = 0; u < 16; ++u) c[u] = csr[p + u];
    float2 f[16];
#pragma unroll
    for (int u = 0; u < 16; ++u) f[u] = __half22float2(h[((c[u] & 0xFFFFu) << 6) + lane]);
#pragma unroll
    for (int u = 0; u < 16; ++u) {
      float w = __half2float(__ushort_as_half((unsigned short)(c[u] >> 16)));
      sx += w * f[u].x;
      sy += w * f[u].y;
    }
  }
  for (; p + 4 <= p1; p += 4) {
    unsigned c[4];
#pragma unroll
    for (int u = 0; u < 4; ++u) c[u] = csr[p + u];
    float2 f[4];
#pragma unroll
    for (int u = 0; u < 4; ++u) f[u] = __half22float2(h[((c[u] & 0xFFFFu) << 6) + lane]);
#pragma unroll
    for (int u = 0; u < 4; ++u) {
      float w = __half2float(__ushort_as_half((unsigned short)(c[u] >> 16)));
      sx += w * f[u].x;
      sy += w * f[u].y;
    }
  }
  for (; p < p1; ++p) {
    unsigned c0 = csr[p];
    float2 f0 = __half22float2(h[((c0 & 0xFFFFu) << 6) + lane]);
    float w = __half2float(__ushort_as_half((unsigned short)(c0 >> 16)));
    sx += w * f0.x;
    sy += w * f0.y;
  }
  float2 bb = ((const float2*)bias)[lane];
  float m0 = mish_f(di * (sx + self.x) + bb.x);
  float m1 = mish_f(di * (sy + self.y) + bb.y);
  float p8[8];
#pragma unroll
  for (int k = 0; k < 8; ++k) {
    float2 wv = wl2[k][lane];
    p8[k] = m0 * wv.x + m1 * wv.y;
  }
  // reduce-scatter: fold k-dim while reducing groups (bits 5,4,3)
  bool b5 = (lane & 32u) != 0u, b4 = (lane & 16u) != 0u, b3 = (lane & 8u) != 0u;
  float q4[4];
#pragma unroll
  for (int j = 0; j < 4; ++j) {
    float send = b5 ? p8[j] : p8[j + 4];
    float r = __shfl_xor(send, 32);
    q4[j] = (b5 ? p8[j + 4] : p8[j]) + r;
  }
  float q2[2];
#pragma unroll
  for (int j = 0; j < 2; ++j) {
    float send = b4 ? q4[j] : q4[j + 2];
    float r = __shfl_xor(send, 16);
    q2[j] = (b4 ? q4[j + 2] : q4[j]) + r;
  }
  float v;
  {
    float send = b3 ? q2[0] : q2[1];
    float r = __shfl_xor(send, 8);
    v = (b3 ? q2[1] : q2[0]) + r;
  }
  // intra-8 butterfly (bits 0,1,2) completes the 64-lane sum
  v += __shfl_xor(v, 1);
  v += __shfl_xor(v, 2);
  v += __shfl_xor(v, 4);
  // lane l holds total for k=(l>>3); lanes with l&7==0 write
  if ((lane & 7u) == 0u) {
    int k = (int)(lane >> 3);
    o8[(size_t)n * 8 + k] = mish_f(v + rb[k]);
  }
}

// ---- fc1 split-K: z += feats[g, kc:kc+128] @ w[kc:kc+128, :] -------------
// fc1 bias omitted: BatchNorm (training mode) is invariant to a per-feature
// constant added to z (it shifts mu equally).
__global__ __launch_bounds__(448) void k_fc1(const float* __restrict__ feats, const float* __restrict__ w,
                                             float* __restrict__ z) {
  __shared__ float fs[8][128];
  int t = threadIdx.x;
  int kc = blockIdx.x * 128;
  int g0 = blockIdx.y * 8;
  for (int i = t; i < 1024; i += 448) {
    int g = i >> 7, k = i & 127;
    fs[g][k] = feats[(size_t)(g0 + g) * 3200 + kc + k];
  }
  __syncthreads();
  if (t < 400) {
    float a[8];
#pragma unroll
    for (int g = 0; g < 8; ++g) a[g] = 0.0f;
    for (int k = 0; k < 128; ++k) {
      float wv = w[(size_t)(kc + k) * 400 + t];
#pragma unroll
      for (int g = 0; g < 8; ++g) a[g] += fs[g][k] * wv;
    }
#pragma unroll
    for (int g = 0; g < 8; ++g) atomicAdd(&z[(size_t)(g0 + g) * 400 + t], a[g]);
  }
}

// ---- batchnorm stats: one block per feature, thread = batch element ------
__global__ __launch_bounds__(128) void k_bn(const float* __restrict__ z, const float* __restrict__ gamma,
                                            const float* __restrict__ beta, float* __restrict__ gs,
                                            float* __restrict__ gb) {
  int j = blockIdx.x;
  int b = threadIdx.x;
  float v = z[b * 400 + j];
  float s = v, s2 = v * v;
#pragma unroll
  for (int off = 1; off < 64; off <<= 1) {
    s += __shfl_xor(s, off);
    s2 += __shfl_xor(s2, off);
  }
  __shared__ float ls[2], ls2[2];
  if ((b & 63) == 0) {
    ls[b >> 6] = s;
    ls2[b >> 6] = s2;
  }
  __syncthreads();
  if (b == 0) {
    float mu = (ls[0] + ls[1]) * (1.0f / 128.0f);
    float var = (ls2[0] + ls2[1]) * (1.0f / 128.0f) - mu * mu;
    float rs = rsqrtf(var + 1e-5f);
    float g = gamma[j] * rs;
    gs[j] = g;
    gb[j] = beta[j] - mu * g;
  }
}

// ---- fc2: one block per graph, block-reduce over j -----------------------
__global__ __launch_bounds__(256) void k_fc2(const float* __restrict__ z, const float* __restrict__ gs,
                                             const float* __restrict__ gb, const float* __restrict__ w2,
                                             const float* __restrict__ b2, float* __restrict__ out) {
  int bg = blockIdx.x;
  int t = threadIdx.x;
  float a0 = 0.f, a1 = 0.f;
  for (int j = t; j < 400; j += 256) {
    float zn = z[bg * 400 + j] * gs[j] + gb[j];
    float m = mish_f(zn);
    a0 += m * w2[j * 2];
    a1 += m * w2[j * 2 + 1];
  }
#pragma unroll
  for (int off = 1; off < 64; off <<= 1) {
    a0 += __shfl_xor(a0, off);
    a1 += __shfl_xor(a1, off);
  }
  __shared__ float s0[4], s1[4];
  if ((t & 63) == 0) {
    s0[t >> 6] = a0;
    s1[t >> 6] = a1;
  }
  __syncthreads();
  if (t == 0) {
    out[bg * 2 + 0] = b2[0] + s0[0] + s0[1] + s0[2] + s0[3];
    out[bg * 2 + 1] = b2[1] + s1[0] + s1[1] + s1[2] + s1[3];
  }
}

extern "C" void kernel_launch(void* const* d_in, const int* in_sizes, int n_in,
                              void* d_out, int out_size, void* d_ws, size_t ws_size,
                              hipStream_t stream) {
  (void)in_sizes; (void)n_in; (void)out_size; (void)ws_size;
  const float* x   = (const float*)d_in[0];
  const int*   ei  = (const int*)d_in[1];
  const float* ew  = (const float*)d_in[2];
  const float* c1w = (const float*)d_in[4];
  const float* c1b = (const float*)d_in[5];
  const float* c2w = (const float*)d_in[6];
  const float* c2b = (const float*)d_in[7];
  const float* rw  = (const float*)d_in[8];
  const float* rb  = (const float*)d_in[9];
  const float* f1w = (const float*)d_in[10];
  const float* bng = (const float*)d_in[12];
  const float* bnb = (const float*)d_in[13];
  const float* f2w = (const float*)d_in[14];
  const float* f2b = (const float*)d_in[15];
  float* out = (float*)d_out;

  char* ws = (char*)d_ws;
  size_t off = 0;
  auto alloc = [&](size_t bytes) {
    void* p = ws + off;
    off = (off + bytes + 255) & ~(size_t)255;
    return p;
  };
  float* dinv    = (float*)alloc((size_t)NN * 4);
  int2*  bounds  = (int2*)alloc((size_t)NN * 8);
  unsigned* gcnt = (unsigned*)alloc(NBKT * 4);               // bucket totals (zeroed by memset)
  unsigned* csr  = (unsigned*)alloc((size_t)NBKT * ECAP * 4);  // 9.8 MB packed
  __half* A1     = (__half*)alloc((size_t)NN * F * 2);       // gemm out (fp16, dinv-scaled)
  __half* B1     = (__half*)alloc((size_t)NN * F * 2);       // agg1 out (fp16)
  _Float16* Wt1  = (_Float16*)alloc((size_t)400 * 128 * 2);
  _Float16* Wt2  = (_Float16*)alloc((size_t)128 * 128 * 2);
  float* o8      = (float*)alloc((size_t)NN * 8 * 4);
  float* z       = (float*)alloc((size_t)128 * 400 * 4);
  float* gs      = (float*)alloc(400 * 4);
  float* gb      = (float*)alloc(400 * 4);

  // E (19.7 MB = NBKT*ECAP*8) aliases A1+B1 (26.2 MB contiguous): E's last
  // reader (k_fprep) completes before gemm1 writes A1 (stream-ordered).
  uint2* E = (uint2*)A1;

  // 9 kernels + 1 tiny memset.
  hipMemsetAsync(gcnt, 0, NBKT * 4, stream);
  k_icsort<<<NB + 264, 256, 0, stream>>>(ei, ew, gcnt, E, c1w, c2w, Wt1, Wt2, z);
  k_fprep<<<NBKT, 1024, 0, stream>>>(E, gcnt, bounds, dinv, csr);

  // conv1: h" = dinv*(x@W1) (MFMA) ; agg+bias+mish
  k_gemm16<true><<<NN / 128, 256, 0, stream>>>(x, Wt1, dinv, A1, 400);
  k_agg<<<NN / 4, 256, 0, stream>>>((const __half2*)A1, bounds, csr, dinv, c1b, (__half2*)B1);
  // conv2 + fused readout -> o8 (feats)
  k_gemm16<false><<<NN / 128, 256, 0, stream>>>(B1, Wt2, dinv, A1, 128);
  k_agg2ro<<<NN / 4, 256, 0, stream>>>((const __half2*)A1, bounds, csr, dinv, c2b, rw, rb, o8);

  {
    dim3 g(25, 16);
    k_fc1<<<g, 448, 0, stream>>>(o8, f1w, z);
  }
  k_bn<<<400, 128, 0, stream>>>(z, bng, bnb, gs, gb);
  k_fc2<<<128, 256, 0, stream>>>(z, gs, gb, f2w, f2b, out);
}

// Round 12
// 399.449 us; speedup vs baseline: 1.5947x; 1.0056x over previous
//
#include <hip/hip_runtime.h>
#include <hip/hip_fp16.h>
#include <math.h>

#define NN 51200
#define NE 2048000
#define F 128
#define NB 1000        // sort blocks
#define EPB 2048       // edges per sort block (NB*EPB == NE)
#define NBKT 200       // buckets (dst >> 8)
#define ECAP 12288     // per-bucket edge capacity (mean 10240, max dev ~20 sigma)
#define TRB 250        // f1w transpose tail blocks in k_icsort

typedef _Float16 half8 __attribute__((ext_vector_type(8)));
typedef float floatx4 __attribute__((ext_vector_type(4)));

__device__ __forceinline__ float mish_f(float x) {
  if (x > 20.0f) return x;
  float e = __expf(x);
  float w = 1.0f + e;
  w = w * w;
  return x * (w - 1.0f) / (w + 1.0f);
}

// ---- k_icsort: blocks 0..999: LDS-cached bucket sort of the edge list ----
// blocks 1000..1263: W1/W2 transpose to fp16.
// blocks 1264..1513: f1w [3200][400] fp32 -> Wtf [400][3200] fp16.
__global__ __launch_bounds__(256) void k_icsort(const int* __restrict__ ei, const float* __restrict__ ew,
                                                unsigned* __restrict__ gcnt, uint2* __restrict__ E,
                                                const float* __restrict__ W1, const float* __restrict__ W2,
                                                _Float16* __restrict__ Wt1, _Float16* __restrict__ Wt2,
                                                const float* __restrict__ f1w, _Float16* __restrict__ Wtf) {
  int bid = blockIdx.x, t = threadIdx.x;
  if (bid < NB) {
    __shared__ uint2 ebuf[EPB];            // 16 KB: packed (src|dstLow, w)
    __shared__ unsigned char bkt[EPB];     // 2 KB
    __shared__ unsigned hist[NBKT];
    __shared__ unsigned base[NBKT];
    for (int i = t; i < NBKT; i += 256) hist[i] = 0u;
    __syncthreads();
    int off0 = bid * EPB;
    for (int it = 0; it < EPB; it += 256) {
      int e = off0 + it + t;
      int dst = ei[NE + e];
      int src = ei[e];
      float w = ew[e];
      ebuf[it + t] = make_uint2((unsigned)src | ((unsigned)(dst & 255) << 16), __float_as_uint(w));
      int b = dst >> 8;
      bkt[it + t] = (unsigned char)b;
      atomicAdd(&hist[b], 1u);
    }
    __syncthreads();
    for (int i = t; i < NBKT; i += 256)
      base[i] = (unsigned)i * ECAP + atomicAdd(&gcnt[i], hist[i]);
    __syncthreads();
    for (int it = 0; it < EPB; it += 256) {
      int j = it + t;
      unsigned b = bkt[j];
      unsigned pos = atomicAdd(&base[b], 1u);
      E[pos] = ebuf[j];
    }
  } else if (bid < NB + 264) {
    int idx = (bid - NB) * 256 + t;  // 0..67583 = 51200 (W1) + 16384 (W2)
    if (idx < 51200) {
      int k = idx >> 7, n = idx & 127;
      Wt1[n * 400 + k] = (_Float16)W1[idx];
    } else {
      int i2 = idx - 51200;
      int k = i2 >> 7, n = i2 & 127;
      Wt2[n * 128 + k] = (_Float16)W2[i2];
    }
  } else {
    // f1w transpose: tile = 16 n-cols x 320 k-rows per block
    int tb = bid - (NB + 264);
    int n0 = (tb % 25) * 16;
    int k0 = (tb / 25) * 320;
    int n = t & 15, kk = t >> 4;
#pragma unroll 4
    for (int i = 0; i < 20; ++i) {
      int k = k0 + kk * 20 + i;
      Wtf[(size_t)(n0 + n) * 3200 + k] = (_Float16)f1w[(size_t)k * 400 + n0 + n];
    }
  }
}

// ---- k_fprep: per-bucket count+degsum -> LDS scan -> bounds/dinv -> scatter
__global__ __launch_bounds__(1024) void k_fprep(const uint2* __restrict__ E, const unsigned* __restrict__ btot,
                                                int2* __restrict__ bounds, float* __restrict__ dinv,
                                                unsigned* __restrict__ csr) {
  __shared__ unsigned lc[256];
  __shared__ float ld[256];
  __shared__ int curs[256];
  __shared__ int ws4[4];
  int b = blockIdx.x, t = threadIdx.x;
  if (t < 256) {
    lc[t] = 0u;
    ld[t] = 0.f;
  }
  __syncthreads();
  unsigned e0 = (unsigned)b * ECAP, e1 = e0 + btot[b];
  for (unsigned e = e0 + t; e < e1; e += 1024) {
    uint2 v = E[e];
    unsigned node = (v.x >> 16) & 255u;
    atomicAdd(&lc[node], 1u);
    atomicAdd(&ld[node], __uint_as_float(v.y));
  }
  __syncthreads();
  int lane = t & 63, wid = (t >> 6) & 3;
  int cv = (t < 256) ? (int)lc[t] : 0;
  int x = cv;
#pragma unroll
  for (int off = 1; off < 64; off <<= 1) {
    int y = __shfl_up(x, off);
    if (lane >= off) x += y;
  }
  if (t < 256 && lane == 63) ws4[wid] = x;
  __syncthreads();
  if (t < 256) {
    int woff = 0;
    for (int k = 0; k < wid; ++k) woff += ws4[k];
    int start = (int)e0 + woff + x - cv;
    bounds[b * 256 + t] = make_int2(start, start + cv);
    dinv[b * 256 + t] = rsqrtf(ld[t] + 1.0f);  // +1 = self-loop weight
    curs[t] = start;
  }
  __syncthreads();
  for (unsigned e = e0 + t; e < e1; e += 1024) {
    uint2 v = E[e];
    unsigned node = (v.x >> 16) & 255u;
    unsigned src = v.x & 0xFFFFu;
    int p = atomicAdd(&curs[node], 1);
    unsigned pk = src | ((unsigned)__half_as_ushort(__float2half_rn(__uint_as_float(v.y))) << 16);
    csr[p] = pk;
  }
}

// ---- MFMA GEMM with dinv row-scale epilogue: C[r] = fp16(dinv[r]*(A@W)[r])
template <bool A_IS_F32>
__global__ __launch_bounds__(256) void k_gemm16(const void* __restrict__ Av,
                                                const _Float16* __restrict__ Wt,
                                                const float* __restrict__ dinv,
                                                __half* __restrict__ C, int K) {
  __shared__ _Float16 As[128][40];
  __shared__ _Float16 Bs[128][40];
  int t = threadIdx.x;
  int bm = blockIdx.x * 128;
  int w = t >> 6, l = t & 63, rr = l & 15, q = l >> 4;
  int si = t >> 1, sj = (t & 1) * 16;

  floatx4 acc[2][8];
#pragma unroll
  for (int a = 0; a < 2; ++a)
#pragma unroll
    for (int b = 0; b < 8; ++b) acc[a][b] = (floatx4){0.f, 0.f, 0.f, 0.f};

  for (int k0 = 0; k0 < K; k0 += 32) {
    if (A_IS_F32) {
      const float* A = (const float*)Av;
      half8 h0, h1;
      if (k0 + sj < K) {
        const float* ap = A + (size_t)(bm + si) * K + k0 + sj;
        float4 v0 = *(const float4*)(ap + 0);
        float4 v1 = *(const float4*)(ap + 4);
        float4 v2 = *(const float4*)(ap + 8);
        float4 v3 = *(const float4*)(ap + 12);
        h0 = (half8){(_Float16)v0.x, (_Float16)v0.y, (_Float16)v0.z, (_Float16)v0.w,
                     (_Float16)v1.x, (_Float16)v1.y, (_Float16)v1.z, (_Float16)v1.w};
        h1 = (half8){(_Float16)v2.x, (_Float16)v2.y, (_Float16)v2.z, (_Float16)v2.w,
                     (_Float16)v3.x, (_Float16)v3.y, (_Float16)v3.z, (_Float16)v3.w};
      } else {
        h0 = (half8){0, 0, 0, 0, 0, 0, 0, 0};
        h1 = h0;
      }
      *(half8*)&As[si][sj] = h0;
      *(half8*)&As[si][sj + 8] = h1;
    } else {
      const __half* A = (const __half*)Av;
      uint4 u0, u1;
      if (k0 + sj < K) {
        const __half* ap = A + (size_t)(bm + si) * K + k0 + sj;
        u0 = *(const uint4*)ap;
        u1 = *(const uint4*)(ap + 8);
      } else {
        u0 = make_uint4(0, 0, 0, 0);
        u1 = u0;
      }
      *(uint4*)&As[si][sj] = u0;
      *(uint4*)&As[si][sj + 8] = u1;
    }
    {
      uint4 u0, u1;
      if (k0 + sj < K) {
        const _Float16* wp = Wt + (size_t)si * K + k0 + sj;
        u0 = *(const uint4*)wp;
        u1 = *(const uint4*)(wp + 8);
      } else {
        u0 = make_uint4(0, 0, 0, 0);
        u1 = u0;
      }
      *(uint4*)&Bs[si][sj] = u0;
      *(uint4*)&Bs[si][sj + 8] = u1;
    }
    __syncthreads();

    half8 a0 = *(const half8*)&As[w * 32 + rr][q * 8];
    half8 a1 = *(const half8*)&As[w * 32 + 16 + rr][q * 8];
#pragma unroll
    for (int nt = 0; nt < 8; ++nt) {
      half8 b = *(const half8*)&Bs[nt * 16 + rr][q * 8];
      acc[0][nt] = __builtin_amdgcn_mfma_f32_16x16x32_f16(a0, b, acc[0][nt], 0, 0, 0);
      acc[1][nt] = __builtin_amdgcn_mfma_f32_16x16x32_f16(a1, b, acc[1][nt], 0, 0, 0);
    }
    __syncthreads();
  }
#pragma unroll
  for (int mt = 0; mt < 2; ++mt) {
    float dv[4];
#pragma unroll
    for (int r4 = 0; r4 < 4; ++r4) dv[r4] = dinv[bm + w * 32 + mt * 16 + q * 4 + r4];
#pragma unroll
    for (int nt = 0; nt < 8; ++nt)
#pragma unroll
      for (int r4 = 0; r4 < 4; ++r4) {
        int row = bm + w * 32 + mt * 16 + q * 4 + r4;
        C[(size_t)row * 128 + nt * 16 + rr] = __float2half(dv[r4] * acc[mt][nt][r4]);
      }
  }
}

// ---- conv1 agg: out[n] = mish(di*(sum ew*h"[src] + h"[n]) + bias) --------
__global__ __launch_bounds__(256) void k_agg(const __half2* __restrict__ h, const int2* __restrict__ bounds,
                                             const unsigned* __restrict__ csr, const float* __restrict__ dinv,
                                             const float* __restrict__ bias, __half2* __restrict__ out) {
  unsigned lane = threadIdx.x & 63u;
  int n = blockIdx.x * 4 + (threadIdx.x >> 6);
  float di = dinv[n];
  float2 self = __half22float2(h[((unsigned)n << 6) + lane]);
  float sx = 0.f, sy = 0.f;
  int2 bd = bounds[n];
  int p = __builtin_amdgcn_readfirstlane(bd.x);
  int p1 = __builtin_amdgcn_readfirstlane(bd.y);
  for (; p + 16 <= p1; p += 16) {
    unsigned c[16];
#pragma unroll
    for (int u = 0; u < 16; ++u) c[u] = csr[p + u];
    float2 f[16];
#pragma unroll
    for (int u = 0; u < 16; ++u) f[u] = __half22float2(h[((c[u] & 0xFFFFu) << 6) + lane]);
#pragma unroll
    for (int u = 0; u < 16; ++u) {
      float w = __half2float(__ushort_as_half((unsigned short)(c[u] >> 16)));
      sx += w * f[u].x;
      sy += w * f[u].y;
    }
  }
  for (; p + 4 <= p1; p += 4) {
    unsigned c[4];
#pragma unroll
    for (int u = 0; u < 4; ++u) c[u] = csr[p + u];
    float2 f[4];
#pragma unroll
    for (int u = 0; u < 4; ++u) f[u] = __half22float2(h[((c[u] & 0xFFFFu) << 6) + lane]);
#pragma unroll
    for (int u = 0; u < 4; ++u) {
      float w = __half2float(__ushort_as_half((unsigned short)(c[u] >> 16)));
      sx += w * f[u].x;
      sy += w * f[u].y;
    }
  }
  for (; p < p1; ++p) {
    unsigned c0 = csr[p];
    float2 f0 = __half22float2(h[((c0 & 0xFFFFu) << 6) + lane]);
    float w = __half2float(__ushort_as_half((unsigned short)(c0 >> 16)));
    sx += w * f0.x;
    sy += w * f0.y;
  }
  float2 bb = ((const float2*)bias)[lane];
  float ax = di * (sx + self.x) + bb.x;
  float ay = di * (sy + self.y) + bb.y;
  out[((unsigned)n << 6) + lane] = __floats2half2_rn(mish_f(ax), mish_f(ay));
}

// ---- conv2 agg FUSED with readout: o8h[n][k] (fp16) ----------------------
// Reduce-scatter readout (10 shfl, lane-coverage proven in r11).
__global__ __launch_bounds__(256) void k_agg2ro(const __half2* __restrict__ h, const int2* __restrict__ bounds,
                                                const unsigned* __restrict__ csr, const float* __restrict__ dinv,
                                                const float* __restrict__ bias, const float* __restrict__ rw,
                                                const float* __restrict__ rb, __half* __restrict__ o8h) {
  __shared__ float2 wl2[8][64];
  int t = threadIdx.x;
  for (int i = t; i < 512; i += 256) {
    int k = i >> 6, l = i & 63;
    wl2[k][l] = make_float2(rw[(2 * l) * 8 + k], rw[(2 * l + 1) * 8 + k]);
  }
  __syncthreads();
  unsigned lane = t & 63u;
  int n = blockIdx.x * 4 + (t >> 6);
  float di = dinv[n];
  float2 self = __half22float2(h[((unsigned)n << 6) + lane]);
  float sx = 0.f, sy = 0.f;
  int2 bd = bounds[n];
  int p = __builtin_amdgcn_readfirstlane(bd.x);
  int p1 = __builtin_amdgcn_readfirstlane(bd.y);
  for (; p + 16 <= p1; p += 16) {
    unsigned c[16];
#pragma unroll
    for (int u = 0; u < 16; ++u) c[u] = csr[p + u];
    float2 f[16];
#pragma unroll
    for (int u = 0; u < 16; ++u) f[u] = __half22float2(h[((c[u] & 0xFFFFu) << 6) + lane]);
#pragma unroll
    for (int u = 0; u < 16; ++u) {
      float w = __half2float(__ushort_as_half((unsigned short)(c[u] >> 16)));
      sx += w * f[u].x;
      sy += w * f[u].y;
    }
  }
  for (; p + 4 <= p1; p += 4) {
    unsigned c[4];
#pragma unroll
    for (int u = 0; u < 4; ++u) c[u] = csr[p + u];
    float2 f[4];
#pragma unroll
    for (int u = 0; u < 4; ++u) f[u] = __half22float2(h[((c[u] & 0xFFFFu) << 6) + lane]);
#pragma unroll
    for (int u = 0; u < 4; ++u) {
      float w = __half2float(__ushort_as_half((unsigned short)(c[u] >> 16)));
      sx += w * f[u].x;
      sy += w * f[u].y;
    }
  }
  for (; p < p1; ++p) {
    unsigned c0 = csr[p];
    float2 f0 = __half22float2(h[((c0 & 0xFFFFu) << 6) + lane]);
    float w = __half2float(__ushort_as_half((unsigned short)(c0 >> 16)));
    sx += w * f0.x;
    sy += w * f0.y;
  }
  float2 bb = ((const float2*)bias)[lane];
  float m0 = mish_f(di * (sx + self.x) + bb.x);
  float m1 = mish_f(di * (sy + self.y) + bb.y);
  float p8[8];
#pragma unroll
  for (int k = 0; k < 8; ++k) {
    float2 wv = wl2[k][lane];
    p8[k] = m0 * wv.x + m1 * wv.y;
  }
  bool b5 = (lane & 32u) != 0u, b4 = (lane & 16u) != 0u, b3 = (lane & 8u) != 0u;
  float q4[4];
#pragma unroll
  for (int j = 0; j < 4; ++j) {
    float send = b5 ? p8[j] : p8[j + 4];
    float r = __shfl_xor(send, 32);
    q4[j] = (b5 ? p8[j + 4] : p8[j]) + r;
  }
  float q2[2];
#pragma unroll
  for (int j = 0; j < 2; ++j) {
    float send = b4 ? q4[j] : q4[j + 2];
    float r = __shfl_xor(send, 16);
    q2[j] = (b4 ? q4[j + 2] : q4[j]) + r;
  }
  float v;
  {
    float send = b3 ? q2[0] : q2[1];
    float r = __shfl_xor(send, 8);
    v = (b3 ? q2[1] : q2[0]) + r;
  }
  v += __shfl_xor(v, 1);
  v += __shfl_xor(v, 2);
  v += __shfl_xor(v, 4);
  if ((lane & 7u) == 0u) {
    int k = (int)(lane >> 3);
    o8h[(size_t)n * 8 + k] = __float2half(mish_f(v + rb[k]));
  }
}

// ---- fc1 as MFMA GEMM: zp[ky] = feats[128,3200] @ f1w (K-chunked) --------
// A = o8h (feats fp16, row-major [128][3200]); B = Wtf [400][3200] fp16.
// Grid (25 n-tiles of 16, 4 K-chunks of 800); plain-store partials, no
// atomics, no z-init. fc1 bias omitted (BN mean-invariance).
__global__ __launch_bounds__(256) void k_fc1m(const __half* __restrict__ A, const _Float16* __restrict__ Bt,
                                              float* __restrict__ zp) {
  __shared__ _Float16 As[128][40];
  __shared__ _Float16 Bs[16][40];
  int t = threadIdx.x;
  int n0 = blockIdx.x * 16;
  int kbase = blockIdx.y * 800;
  int w = t >> 6, l = t & 63, rr = l & 15, q = l >> 4;
  int si = t >> 1, sj = (t & 1) * 16;
  floatx4 acc[2];
  acc[0] = (floatx4){0.f, 0.f, 0.f, 0.f};
  acc[1] = (floatx4){0.f, 0.f, 0.f, 0.f};
  for (int k0 = kbase; k0 < kbase + 800; k0 += 32) {
    *(uint4*)&As[si][sj] = *(const uint4*)(A + (size_t)si * 3200 + k0 + sj);
    *(uint4*)&As[si][sj + 8] = *(const uint4*)(A + (size_t)si * 3200 + k0 + sj + 8);
    if (t < 64) {
      int ni = t >> 2, s2 = (t & 3) * 8;
      *(uint4*)&Bs[ni][s2] = *(const uint4*)(Bt + (size_t)(n0 + ni) * 3200 + k0 + s2);
    }
    __syncthreads();
    half8 a0 = *(const half8*)&As[w * 32 + rr][q * 8];
    half8 a1 = *(const half8*)&As[w * 32 + 16 + rr][q * 8];
    half8 b = *(const half8*)&Bs[rr][q * 8];
    acc[0] = __builtin_amdgcn_mfma_f32_16x16x32_f16(a0, b, acc[0], 0, 0, 0);
    acc[1] = __builtin_amdgcn_mfma_f32_16x16x32_f16(a1, b, acc[1], 0, 0, 0);
    __syncthreads();
  }
  float* zo = zp + (size_t)blockIdx.y * 51200;
#pragma unroll
  for (int mt = 0; mt < 2; ++mt)
#pragma unroll
    for (int r4 = 0; r4 < 4; ++r4) {
      int row = w * 32 + mt * 16 + q * 4 + r4;
      zo[row * 400 + n0 + rr] = acc[mt][r4];
    }
}

// ---- batchnorm stats over summed partials --------------------------------
__global__ __launch_bounds__(128) void k_bn(const float* __restrict__ zp, const float* __restrict__ gamma,
                                            const float* __restrict__ beta, float* __restrict__ gs,
                                            float* __restrict__ gb) {
  int j = blockIdx.x;
  int b = threadIdx.x;
  int idx = b * 400 + j;
  float v = zp[idx] + zp[51200 + idx] + zp[102400 + idx] + zp[153600 + idx];
  float s = v, s2 = v * v;
#pragma unroll
  for (int off = 1; off < 64; off <<= 1) {
    s += __shfl_xor(s, off);
    s2 += __shfl_xor(s2, off);
  }
  __shared__ float ls[2], ls2[2];
  if ((b & 63) == 0) {
    ls[b >> 6] = s;
    ls2[b >> 6] = s2;
  }
  __syncthreads();
  if (b == 0) {
    float mu = (ls[0] + ls[1]) * (1.0f / 128.0f);
    float var = (ls2[0] + ls2[1]) * (1.0f / 128.0f) - mu * mu;
    float rs = rsqrtf(var + 1e-5f);
    float g = gamma[j] * rs;
    gs[j] = g;
    gb[j] = beta[j] - mu * g;
  }
}

// ---- fc2 over summed partials --------------------------------------------
__global__ __launch_bounds__(256) void k_fc2(const float* __restrict__ zp, const float* __restrict__ gs,
                                             const float* __restrict__ gb, const float* __restrict__ w2,
                                             const float* __restrict__ b2, float* __restrict__ out) {
  int bg = blockIdx.x;
  int t = threadIdx.x;
  float a0 = 0.f, a1 = 0.f;
  for (int j = t; j < 400; j += 256) {
    int idx = bg * 400 + j;
    float zv = zp[idx] + zp[51200 + idx] + zp[102400 + idx] + zp[153600 + idx];
    float zn = zv * gs[j] + gb[j];
    float m = mish_f(zn);
    a0 += m * w2[j * 2];
    a1 += m * w2[j * 2 + 1];
  }
#pragma unroll
  for (int off = 1; off < 64; off <<= 1) {
    a0 += __shfl_xor(a0, off);
    a1 += __shfl_xor(a1, off);
  }
  __shared__ float s0[4], s1[4];
  if ((t & 63) == 0) {
    s0[t >> 6] = a0;
    s1[t >> 6] = a1;
  }
  __syncthreads();
  if (t == 0) {
    out[bg * 2 + 0] = b2[0] + s0[0] + s0[1] + s0[2] + s0[3];
    out[bg * 2 + 1] = b2[1] + s1[0] + s1[1] + s1[2] + s1[3];
  }
}

extern "C" void kernel_launch(void* const* d_in, const int* in_sizes, int n_in,
                              void* d_out, int out_size, void* d_ws, size_t ws_size,
                              hipStream_t stream) {
  (void)in_sizes; (void)n_in; (void)out_size; (void)ws_size;
  const float* x   = (const float*)d_in[0];
  const int*   ei  = (const int*)d_in[1];
  const float* ew  = (const float*)d_in[2];
  const float* c1w = (const float*)d_in[4];
  const float* c1b = (const float*)d_in[5];
  const float* c2w = (const float*)d_in[6];
  const float* c2b = (const float*)d_in[7];
  const float* rw  = (const float*)d_in[8];
  const float* rb  = (const float*)d_in[9];
  const float* f1w = (const float*)d_in[10];
  const float* bng = (const float*)d_in[12];
  const float* bnb = (const float*)d_in[13];
  const float* f2w = (const float*)d_in[14];
  const float* f2b = (const float*)d_in[15];
  float* out = (float*)d_out;

  char* ws = (char*)d_ws;
  size_t off = 0;
  auto alloc = [&](size_t bytes) {
    void* p = ws + off;
    off = (off + bytes + 255) & ~(size_t)255;
    return p;
  };
  float* dinv    = (float*)alloc((size_t)NN * 4);
  int2*  bounds  = (int2*)alloc((size_t)NN * 8);
  unsigned* gcnt = (unsigned*)alloc(NBKT * 4);               // bucket totals (zeroed by memset)
  unsigned* csr  = (unsigned*)alloc((size_t)NBKT * ECAP * 4);  // 9.8 MB packed
  __half* A1     = (__half*)alloc((size_t)NN * F * 2);       // gemm out (fp16, dinv-scaled)
  __half* B1     = (__half*)alloc((size_t)NN * F * 2);       // agg1 out (fp16)
  _Float16* Wt1  = (_Float16*)alloc((size_t)400 * 128 * 2);
  _Float16* Wt2  = (_Float16*)alloc((size_t)128 * 128 * 2);
  _Float16* Wtf  = (_Float16*)alloc((size_t)400 * 3200 * 2); // fc1 weight fp16 T (2.56 MB)
  __half* o8h    = (__half*)alloc((size_t)NN * 8 * 2);       // feats fp16 (819 KB)
  float* zp      = (float*)alloc((size_t)4 * 128 * 400 * 4); // fc1 partials (819 KB)
  float* gs      = (float*)alloc(400 * 4);
  float* gb      = (float*)alloc(400 * 4);

  // E (19.7 MB = NBKT*ECAP*8) aliases A1+B1 (26.2 MB contiguous): E's last
  // reader (k_fprep) completes before gemm1 writes A1 (stream-ordered).
  uint2* E = (uint2*)A1;

  // 9 kernels + 1 tiny memset.
  hipMemsetAsync(gcnt, 0, NBKT * 4, stream);
  k_icsort<<<NB + 264 + TRB, 256, 0, stream>>>(ei, ew, gcnt, E, c1w, c2w, Wt1, Wt2, f1w, Wtf);
  k_fprep<<<NBKT, 1024, 0, stream>>>(E, gcnt, bounds, dinv, csr);

  // conv1: h" = dinv*(x@W1) (MFMA) ; agg+bias+mish
  k_gemm16<true><<<NN / 128, 256, 0, stream>>>(x, Wt1, dinv, A1, 400);
  k_agg<<<NN / 4, 256, 0, stream>>>((const __half2*)A1, bounds, csr, dinv, c1b, (__half2*)B1);
  // conv2 + fused readout -> o8h (feats, fp16)
  k_gemm16<false><<<NN / 128, 256, 0, stream>>>(B1, Wt2, dinv, A1, 128);
  k_agg2ro<<<NN / 4, 256, 0, stream>>>((const __half2*)A1, bounds, csr, dinv, c2b, rw, rb, o8h);

  // fc1 as MFMA (no atomics, plain-store K-partials)
  {
    dim3 g(25, 4);
    k_fc1m<<<g, 256, 0, stream>>>(o8h, Wtf, zp);
  }
  k_bn<<<400, 128, 0, stream>>>(zp, bng, bnb, gs, gb);
  k_fc2<<<128, 256, 0, stream>>>(zp, gs, gb, f2w, f2b, out);
}

// Round 14
// 397.060 us; speedup vs baseline: 1.6043x; 1.0060x over previous
//
#include <hip/hip_runtime.h>
#include <hip/hip_fp16.h>
#include <math.h>

#define NN 51200
#define NE 2048000
#define F 128
#define NB 1000        // sort blocks
#define EPB 2048       // edges per sort block (NB*EPB == NE)
#define NBKT 200       // buckets (dst >> 8)
#define ECAP 12288     // per-bucket edge capacity (mean 10240, max dev ~20 sigma)
#define TRB 250        // f1w transpose tail blocks in k_icsort

typedef _Float16 half8 __attribute__((ext_vector_type(8)));
typedef float floatx4 __attribute__((ext_vector_type(4)));

__device__ __forceinline__ float mish_f(float x) {
  if (x > 20.0f) return x;
  float e = __expf(x);
  float w = 1.0f + e;
  w = w * w;
  return x * (w - 1.0f) / (w + 1.0f);
}

// ---- k_icsort: blocks 0..999: LDS-cached bucket sort of the edge list ----
// blocks 1000..1263: W1/W2 transpose to fp16.
// blocks 1264..1513: f1w [3200][400] fp32 -> Wtf [400][3200] fp16.
__global__ __launch_bounds__(256) void k_icsort(const int* __restrict__ ei, const float* __restrict__ ew,
                                                unsigned* __restrict__ gcnt, uint2* __restrict__ E,
                                                const float* __restrict__ W1, const float* __restrict__ W2,
                                                _Float16* __restrict__ Wt1, _Float16* __restrict__ Wt2,
                                                const float* __restrict__ f1w, _Float16* __restrict__ Wtf) {
  int bid = blockIdx.x, t = threadIdx.x;
  if (bid < NB) {
    __shared__ uint2 ebuf[EPB];            // 16 KB: packed (src|dstLow, w)
    __shared__ unsigned char bkt[EPB];     // 2 KB
    __shared__ unsigned hist[NBKT];
    __shared__ unsigned base[NBKT];
    for (int i = t; i < NBKT; i += 256) hist[i] = 0u;
    __syncthreads();
    int off0 = bid * EPB;
    for (int it = 0; it < EPB; it += 256) {
      int e = off0 + it + t;
      int dst = ei[NE + e];
      int src = ei[e];
      float w = ew[e];
      ebuf[it + t] = make_uint2((unsigned)src | ((unsigned)(dst & 255) << 16), __float_as_uint(w));
      int b = dst >> 8;
      bkt[it + t] = (unsigned char)b;
      atomicAdd(&hist[b], 1u);
    }
    __syncthreads();
    for (int i = t; i < NBKT; i += 256)
      base[i] = (unsigned)i * ECAP + atomicAdd(&gcnt[i], hist[i]);
    __syncthreads();
    for (int it = 0; it < EPB; it += 256) {
      int j = it + t;
      unsigned b = bkt[j];
      unsigned pos = atomicAdd(&base[b], 1u);
      E[pos] = ebuf[j];
    }
  } else if (bid < NB + 264) {
    int idx = (bid - NB) * 256 + t;  // 0..67583 = 51200 (W1) + 16384 (W2)
    if (idx < 51200) {
      int k = idx >> 7, n = idx & 127;
      Wt1[n * 400 + k] = (_Float16)W1[idx];
    } else {
      int i2 = idx - 51200;
      int k = i2 >> 7, n = i2 & 127;
      Wt2[n * 128 + k] = (_Float16)W2[i2];
    }
  } else {
    // f1w transpose: tile = 16 n-cols x 320 k-rows per block
    int tb = bid - (NB + 264);
    int n0 = (tb % 25) * 16;
    int k0 = (tb / 25) * 320;
    int n = t & 15, kk = t >> 4;
#pragma unroll 4
    for (int i = 0; i < 20; ++i) {
      int k = k0 + kk * 20 + i;
      Wtf[(size_t)(n0 + n) * 3200 + k] = (_Float16)f1w[(size_t)k * 400 + n0 + n];
    }
  }
}

// ---- k_fprep: SINGLE-PASS LDS-resident bucket processing -----------------
// The whole bucket (<= ECAP edges, 98.3 KB) streams from global ONCE into
// LDS while count+degsum accumulate; scan; scatter to csr from LDS (no
// second global E read -- r12's version paid two full E passes).
// LDS ~101 KB -> 1 block/CU, 16 waves (grid 200 <= 256 CUs anyway).
__global__ __launch_bounds__(1024) void k_fprep(const uint2* __restrict__ E, const unsigned* __restrict__ btot,
                                                int2* __restrict__ bounds, float* __restrict__ dinv,
                                                unsigned* __restrict__ csr) {
  __shared__ uint2 eb[ECAP];       // 98.3 KB
  __shared__ unsigned lc[256];
  __shared__ float ld[256];
  __shared__ int curs[256];
  __shared__ int ws4[4];
  int b = blockIdx.x, t = threadIdx.x;
  if (t < 256) {
    lc[t] = 0u;
    ld[t] = 0.f;
  }
  __syncthreads();
  unsigned cnt = btot[b];
  unsigned e0 = (unsigned)b * ECAP;
  for (unsigned i = t; i < cnt; i += 1024) {
    uint2 v = E[e0 + i];
    eb[i] = v;
    unsigned node = (v.x >> 16) & 255u;
    atomicAdd(&lc[node], 1u);
    atomicAdd(&ld[node], __uint_as_float(v.y));
  }
  __syncthreads();
  // exclusive scan of lc[0..255]; threads >= 256 shuffle garbage harmlessly
  int lane = t & 63, wid = (t >> 6) & 3;
  int cv = (t < 256) ? (int)lc[t] : 0;
  int x = cv;
#pragma unroll
  for (int off = 1; off < 64; off <<= 1) {
    int y = __shfl_up(x, off);
    if (lane >= off) x += y;
  }
  if (t < 256 && lane == 63) ws4[wid] = x;
  __syncthreads();
  if (t < 256) {
    int woff = 0;
    for (int k = 0; k < wid; ++k) woff += ws4[k];
    int start = (int)e0 + woff + x - cv;
    bounds[b * 256 + t] = make_int2(start, start + cv);
    dinv[b * 256 + t] = rsqrtf(ld[t] + 1.0f);  // +1 = self-loop weight
    curs[t] = start;
  }
  __syncthreads();
  for (unsigned i = t; i < cnt; i += 1024) {
    uint2 v = eb[i];
    unsigned node = (v.x >> 16) & 255u;
    unsigned src = v.x & 0xFFFFu;
    int p = atomicAdd(&curs[node], 1);
    unsigned pk = src | ((unsigned)__half_as_ushort(__float2half_rn(__uint_as_float(v.y))) << 16);
    csr[p] = pk;
  }
}

// ---- MFMA GEMM with dinv row-scale epilogue: C[r] = fp16(dinv[r]*(A@W)[r])
template <bool A_IS_F32>
__global__ __launch_bounds__(256) void k_gemm16(const void* __restrict__ Av,
                                                const _Float16* __restrict__ Wt,
                                                const float* __restrict__ dinv,
                                                __half* __restrict__ C, int K) {
  __shared__ _Float16 As[128][40];
  __shared__ _Float16 Bs[128][40];
  int t = threadIdx.x;
  int bm = blockIdx.x * 128;
  int w = t >> 6, l = t & 63, rr = l & 15, q = l >> 4;
  int si = t >> 1, sj = (t & 1) * 16;

  floatx4 acc[2][8];
#pragma unroll
  for (int a = 0; a < 2; ++a)
#pragma unroll
    for (int b = 0; b < 8; ++b) acc[a][b] = (floatx4){0.f, 0.f, 0.f, 0.f};

  for (int k0 = 0; k0 < K; k0 += 32) {
    if (A_IS_F32) {
      const float* A = (const float*)Av;
      half8 h0, h1;
      if (k0 + sj < K) {
        const float* ap = A + (size_t)(bm + si) * K + k0 + sj;
        float4 v0 = *(const float4*)(ap + 0);
        float4 v1 = *(const float4*)(ap + 4);
        float4 v2 = *(const float4*)(ap + 8);
        float4 v3 = *(const float4*)(ap + 12);
        h0 = (half8){(_Float16)v0.x, (_Float16)v0.y, (_Float16)v0.z, (_Float16)v0.w,
                     (_Float16)v1.x, (_Float16)v1.y, (_Float16)v1.z, (_Float16)v1.w};
        h1 = (half8){(_Float16)v2.x, (_Float16)v2.y, (_Float16)v2.z, (_Float16)v2.w,
                     (_Float16)v3.x, (_Float16)v3.y, (_Float16)v3.z, (_Float16)v3.w};
      } else {
        h0 = (half8){0, 0, 0, 0, 0, 0, 0, 0};
        h1 = h0;
      }
      *(half8*)&As[si][sj] = h0;
      *(half8*)&As[si][sj + 8] = h1;
    } else {
      const __half* A = (const __half*)Av;
      uint4 u0, u1;
      if (k0 + sj < K) {
        const __half* ap = A + (size_t)(bm + si) * K + k0 + sj;
        u0 = *(const uint4*)ap;
        u1 = *(const uint4*)(ap + 8);
      } else {
        u0 = make_uint4(0, 0, 0, 0);
        u1 = u0;
      }
      *(uint4*)&As[si][sj] = u0;
      *(uint4*)&As[si][sj + 8] = u1;
    }
    {
      uint4 u0, u1;
      if (k0 + sj < K) {
        const _Float16* wp = Wt + (size_t)si * K + k0 + sj;
        u0 = *(const uint4*)wp;
        u1 = *(const uint4*)(wp + 8);
      } else {
        u0 = make_uint4(0, 0, 0, 0);
        u1 = u0;
      }
      *(uint4*)&Bs[si][sj] = u0;
      *(uint4*)&Bs[si][sj + 8] = u1;
    }
    __syncthreads();

    half8 a0 = *(const half8*)&As[w * 32 + rr][q * 8];
    half8 a1 = *(const half8*)&As[w * 32 + 16 + rr][q * 8];
#pragma unroll
    for (int nt = 0; nt < 8; ++nt) {
      half8 b = *(const half8*)&Bs[nt * 16 + rr][q * 8];
      acc[0][nt] = __builtin_amdgcn_mfma_f32_16x16x32_f16(a0, b, acc[0][nt], 0, 0, 0);
      acc[1][nt] = __builtin_amdgcn_mfma_f32_16x16x32_f16(a1, b, acc[1][nt], 0, 0, 0);
    }
    __syncthreads();
  }
#pragma unroll
  for (int mt = 0; mt < 2; ++mt) {
    float dv[4];
#pragma unroll
    for (int r4 = 0; r4 < 4; ++r4) dv[r4] = dinv[bm + w * 32 + mt * 16 + q * 4 + r4];
#pragma unroll
    for (int nt = 0; nt < 8; ++nt)
#pragma unroll
      for (int r4 = 0; r4 < 4; ++r4) {
        int row = bm + w * 32 + mt * 16 + q * 4 + r4;
        C[(size_t)row * 128 + nt * 16 + rr] = __float2half(dv[r4] * acc[mt][nt][r4]);
      }
  }
}

// ---- conv1 agg: out[n] = mish(di*(sum ew*h"[src] + h"[n]) + bias) --------
__global__ __launch_bounds__(256) void k_agg(const __half2* __restrict__ h, const int2* __restrict__ bounds,
                                             const unsigned* __restrict__ csr, const float* __restrict__ dinv,
                                             const float* __restrict__ bias, __half2* __restrict__ out) {
  unsigned lane = threadIdx.x & 63u;
  int n = blockIdx.x * 4 + (threadIdx.x >> 6);
  float di = dinv[n];
  float2 self = __half22float2(h[((unsigned)n << 6) + lane]);
  float sx = 0.f, sy = 0.f;
  int2 bd = bounds[n];
  int p = __builtin_amdgcn_readfirstlane(bd.x);
  int p1 = __builtin_amdgcn_readfirstlane(bd.y);
  for (; p + 16 <= p1; p += 16) {
    unsigned c[16];
#pragma unroll
    for (int u = 0; u < 16; ++u) c[u] = csr[p + u];
    float2 f[16];
#pragma unroll
    for (int u = 0; u < 16; ++u) f[u] = __half22float2(h[((c[u] & 0xFFFFu) << 6) + lane]);
#pragma unroll
    for (int u = 0; u < 16; ++u) {
      float w = __half2float(__ushort_as_half((unsigned short)(c[u] >> 16)));
      sx += w * f[u].x;
      sy += w * f[u].y;
    }
  }
  for (; p + 4 <= p1; p += 4) {
    unsigned c[4];
#pragma unroll
    for (int u = 0; u < 4; ++u) c[u] = csr[p + u];
    float2 f[4];
#pragma unroll
    for (int u = 0; u < 4; ++u) f[u] = __half22float2(h[((c[u] & 0xFFFFu) << 6) + lane]);
#pragma unroll
    for (int u = 0; u < 4; ++u) {
      float w = __half2float(__ushort_as_half((unsigned short)(c[u] >> 16)));
      sx += w * f[u].x;
      sy += w * f[u].y;
    }
  }
  for (; p < p1; ++p) {
    unsigned c0 = csr[p];
    float2 f0 = __half22float2(h[((c0 & 0xFFFFu) << 6) + lane]);
    float w = __half2float(__ushort_as_half((unsigned short)(c0 >> 16)));
    sx += w * f0.x;
    sy += w * f0.y;
  }
  float2 bb = ((const float2*)bias)[lane];
  float ax = di * (sx + self.x) + bb.x;
  float ay = di * (sy + self.y) + bb.y;
  out[((unsigned)n << 6) + lane] = __floats2half2_rn(mish_f(ax), mish_f(ay));
}

// ---- conv2 agg FUSED with readout: o8h[n][k] (fp16) ----------------------
// Reduce-scatter readout (10 shfl, lane-coverage proven in r11).
__global__ __launch_bounds__(256) void k_agg2ro(const __half2* __restrict__ h, const int2* __restrict__ bounds,
                                                const unsigned* __restrict__ csr, const float* __restrict__ dinv,
                                                const float* __restrict__ bias, const float* __restrict__ rw,
                                                const float* __restrict__ rb, __half* __restrict__ o8h) {
  __shared__ float2 wl2[8][64];
  int t = threadIdx.x;
  for (int i = t; i < 512; i += 256) {
    int k = i >> 6, l = i & 63;
    wl2[k][l] = make_float2(rw[(2 * l) * 8 + k], rw[(2 * l + 1) * 8 + k]);
  }
  __syncthreads();
  unsigned lane = t & 63u;
  int n = blockIdx.x * 4 + (t >> 6);
  float di = dinv[n];
  float2 self = __half22float2(h[((unsigned)n << 6) + lane]);
  float sx = 0.f, sy = 0.f;
  int2 bd = bounds[n];
  int p = __builtin_amdgcn_readfirstlane(bd.x);
  int p1 = __builtin_amdgcn_readfirstlane(bd.y);
  for (; p + 16 <= p1; p += 16) {
    unsigned c[16];
#pragma unroll
    for (int u = 0; u < 16; ++u) c[u] = csr[p + u];
    float2 f[16];
#pragma unroll
    for (int u = 0; u < 16; ++u) f[u] = __half22float2(h[((c[u] & 0xFFFFu) << 6) + lane]);
#pragma unroll
    for (int u = 0; u < 16; ++u) {
      float w = __half2float(__ushort_as_half((unsigned short)(c[u] >> 16)));
      sx += w * f[u].x;
      sy += w * f[u].y;
    }
  }
  for (; p + 4 <= p1; p += 4) {
    unsigned c[4];
#pragma unroll
    for (int u = 0; u < 4; ++u) c[u] = csr[p + u];
    float2 f[4];
#pragma unroll
    for (int u = 0; u < 4; ++u) f[u] = __half22float2(h[((c[u] & 0xFFFFu) << 6) + lane]);
#pragma unroll
    for (int u = 0; u < 4; ++u) {
      float w = __half2float(__ushort_as_half((unsigned short)(c[u] >> 16)));
      sx += w * f[u].x;
      sy += w * f[u].y;
    }
  }
  for (; p < p1; ++p) {
    unsigned c0 = csr[p];
    float2 f0 = __half22float2(h[((c0 & 0xFFFFu) << 6) + lane]);
    float w = __half2float(__ushort_as_half((unsigned short)(c0 >> 16)));
    sx += w * f0.x;
    sy += w * f0.y;
  }
  float2 bb = ((const float2*)bias)[lane];
  float m0 = mish_f(di * (sx + self.x) + bb.x);
  float m1 = mish_f(di * (sy + self.y) + bb.y);
  float p8[8];
#pragma unroll
  for (int k = 0; k < 8; ++k) {
    float2 wv = wl2[k][lane];
    p8[k] = m0 * wv.x + m1 * wv.y;
  }
  bool b5 = (lane & 32u) != 0u, b4 = (lane & 16u) != 0u, b3 = (lane & 8u) != 0u;
  float q4[4];
#pragma unroll
  for (int j = 0; j < 4; ++j) {
    float send = b5 ? p8[j] : p8[j + 4];
    float r = __shfl_xor(send, 32);
    q4[j] = (b5 ? p8[j + 4] : p8[j]) + r;
  }
  float q2[2];
#pragma unroll
  for (int j = 0; j < 2; ++j) {
    float send = b4 ? q4[j] : q4[j + 2];
    float r = __shfl_xor(send, 16);
    q2[j] = (b4 ? q4[j + 2] : q4[j]) + r;
  }
  float v;
  {
    float send = b3 ? q2[0] : q2[1];
    float r = __shfl_xor(send, 8);
    v = (b3 ? q2[1] : q2[0]) + r;
  }
  v += __shfl_xor(v, 1);
  v += __shfl_xor(v, 2);
  v += __shfl_xor(v, 4);
  if ((lane & 7u) == 0u) {
    int k = (int)(lane >> 3);
    o8h[(size_t)n * 8 + k] = __float2half(mish_f(v + rb[k]));
  }
}

// ---- fc1 as MFMA GEMM: zp[ky] = feats[128,3200] @ f1w (K-chunked) --------
__global__ __launch_bounds__(256) void k_fc1m(const __half* __restrict__ A, const _Float16* __restrict__ Bt,
                                              float* __restrict__ zp) {
  __shared__ _Float16 As[128][40];
  __shared__ _Float16 Bs[16][40];
  int t = threadIdx.x;
  int n0 = blockIdx.x * 16;
  int kbase = blockIdx.y * 800;
  int w = t >> 6, l = t & 63, rr = l & 15, q = l >> 4;
  int si = t >> 1, sj = (t & 1) * 16;
  floatx4 acc[2];
  acc[0] = (floatx4){0.f, 0.f, 0.f, 0.f};
  acc[1] = (floatx4){0.f, 0.f, 0.f, 0.f};
  for (int k0 = kbase; k0 < kbase + 800; k0 += 32) {
    *(uint4*)&As[si][sj] = *(const uint4*)(A + (size_t)si * 3200 + k0 + sj);
    *(uint4*)&As[si][sj + 8] = *(const uint4*)(A + (size_t)si * 3200 + k0 + sj + 8);
    if (t < 64) {
      int ni = t >> 2, s2 = (t & 3) * 8;
      *(uint4*)&Bs[ni][s2] = *(const uint4*)(Bt + (size_t)(n0 + ni) * 3200 + k0 + s2);
    }
    __syncthreads();
    half8 a0 = *(const half8*)&As[w * 32 + rr][q * 8];
    half8 a1 = *(const half8*)&As[w * 32 + 16 + rr][q * 8];
    half8 b = *(const half8*)&Bs[rr][q * 8];
    acc[0] = __builtin_amdgcn_mfma_f32_16x16x32_f16(a0, b, acc[0], 0, 0, 0);
    acc[1] = __builtin_amdgcn_mfma_f32_16x16x32_f16(a1, b, acc[1], 0, 0, 0);
    __syncthreads();
  }
  float* zo = zp + (size_t)blockIdx.y * 51200;
#pragma unroll
  for (int mt = 0; mt < 2; ++mt)
#pragma unroll
    for (int r4 = 0; r4 < 4; ++r4) {
      int row = w * 32 + mt * 16 + q * 4 + r4;
      zo[row * 400 + n0 + rr] = acc[mt][r4];
    }
}

// ---- batchnorm stats over summed partials --------------------------------
__global__ __launch_bounds__(128) void k_bn(const float* __restrict__ zp, const float* __restrict__ gamma,
                                            const float* __restrict__ beta, float* __restrict__ gs,
                                            float* __restrict__ gb) {
  int j = blockIdx.x;
  int b = threadIdx.x;
  int idx = b * 400 + j;
  float v = zp[idx] + zp[51200 + idx] + zp[102400 + idx] + zp[153600 + idx];
  float s = v, s2 = v * v;
#pragma unroll
  for (int off = 1; off < 64; off <<= 1) {
    s += __shfl_xor(s, off);
    s2 += __shfl_xor(s2, off);
  }
  __shared__ float ls[2], ls2[2];
  if ((b & 63) == 0) {
    ls[b >> 6] = s;
    ls2[b >> 6] = s2;
  }
  __syncthreads();
  if (b == 0) {
    float mu = (ls[0] + ls[1]) * (1.0f / 128.0f);
    float var = (ls2[0] + ls2[1]) * (1.0f / 128.0f) - mu * mu;
    float rs = rsqrtf(var + 1e-5f);
    float g = gamma[j] * rs;
    gs[j] = g;
    gb[j] = beta[j] - mu * g;
  }
}

// ---- fc2 over summed partials --------------------------------------------
__global__ __launch_bounds__(256) void k_fc2(const float* __restrict__ zp, const float* __restrict__ gs,
                                             const float* __restrict__ gb, const float* __restrict__ w2,
                                             const float* __restrict__ b2, float* __restrict__ out) {
  int bg = blockIdx.x;
  int t = threadIdx.x;
  float a0 = 0.f, a1 = 0.f;
  for (int j = t; j < 400; j += 256) {
    int idx = bg * 400 + j;
    float zv = zp[idx] + zp[51200 + idx] + zp[102400 + idx] + zp[153600 + idx];
    float zn = zv * gs[j] + gb[j];
    float m = mish_f(zn);
    a0 += m * w2[j * 2];
    a1 += m * w2[j * 2 + 1];
  }
#pragma unroll
  for (int off = 1; off < 64; off <<= 1) {
    a0 += __shfl_xor(a0, off);
    a1 += __shfl_xor(a1, off);
  }
  __shared__ float s0[4], s1[4];
  if ((t & 63) == 0) {
    s0[t >> 6] = a0;
    s1[t >> 6] = a1;
  }
  __syncthreads();
  if (t == 0) {
    out[bg * 2 + 0] = b2[0] + s0[0] + s0[1] + s0[2] + s0[3];
    out[bg * 2 + 1] = b2[1] + s1[0] + s1[1] + s1[2] + s1[3];
  }
}

extern "C" void kernel_launch(void* const* d_in, const int* in_sizes, int n_in,
                              void* d_out, int out_size, void* d_ws, size_t ws_size,
                              hipStream_t stream) {
  (void)in_sizes; (void)n_in; (void)out_size; (void)ws_size;
  const float* x   = (const float*)d_in[0];
  const int*   ei  = (const int*)d_in[1];
  const float* ew  = (const float*)d_in[2];
  const float* c1w = (const float*)d_in[4];
  const float* c1b = (const float*)d_in[5];
  const float* c2w = (const float*)d_in[6];
  const float* c2b = (const float*)d_in[7];
  const float* rw  = (const float*)d_in[8];
  const float* rb  = (const float*)d_in[9];
  const float* f1w = (const float*)d_in[10];
  const float* bng = (const float*)d_in[12];
  const float* bnb = (const float*)d_in[13];
  const float* f2w = (const float*)d_in[14];
  const float* f2b = (const float*)d_in[15];
  float* out = (float*)d_out;

  char* ws = (char*)d_ws;
  size_t off = 0;
  auto alloc = [&](size_t bytes) {
    void* p = ws + off;
    off = (off + bytes + 255) & ~(size_t)255;
    return p;
  };
  float* dinv    = (float*)alloc((size_t)NN * 4);
  int2*  bounds  = (int2*)alloc((size_t)NN * 8);
  unsigned* gcnt = (unsigned*)alloc(NBKT * 4);               // bucket totals (zeroed by memset)
  unsigned* csr  = (unsigned*)alloc((size_t)NBKT * ECAP * 4);  // 9.8 MB packed
  __half* A1     = (__half*)alloc((size_t)NN * F * 2);       // gemm out (fp16, dinv-scaled)
  __half* B1     = (__half*)alloc((size_t)NN * F * 2);       // agg1 out (fp16)
  _Float16* Wt1  = (_Float16*)alloc((size_t)400 * 128 * 2);
  _Float16* Wt2  = (_Float16*)alloc((size_t)128 * 128 * 2);
  _Float16* Wtf  = (_Float16*)alloc((size_t)400 * 3200 * 2); // fc1 weight fp16 T (2.56 MB)
  __half* o8h    = (__half*)alloc((size_t)NN * 8 * 2);       // feats fp16 (819 KB)
  float* zp      = (float*)alloc((size_t)4 * 128 * 400 * 4); // fc1 partials (819 KB)
  float* gs      = (float*)alloc(400 * 4);
  float* gb      = (float*)alloc(400 * 4);

  // E (19.7 MB = NBKT*ECAP*8) aliases A1+B1 (26.2 MB contiguous): E's last
  // reader (k_fprep) completes before gemm1 writes A1 (stream-ordered).
  uint2* E = (uint2*)A1;

  // 9 kernels + 1 tiny memset.
  hipMemsetAsync(gcnt, 0, NBKT * 4, stream);
  k_icsort<<<NB + 264 + TRB, 256, 0, stream>>>(ei, ew, gcnt, E, c1w, c2w, Wt1, Wt2, f1w, Wtf);
  k_fprep<<<NBKT, 1024, 0, stream>>>(E, gcnt, bounds, dinv, csr);

  // conv1: h" = dinv*(x@W1) (MFMA) ; agg+bias+mish
  k_gemm16<true><<<NN / 128, 256, 0, stream>>>(x, Wt1, dinv, A1, 400);
  k_agg<<<NN / 4, 256, 0, stream>>>((const __half2*)A1, bounds, csr, dinv, c1b, (__half2*)B1);
  // conv2 + fused readout -> o8h (feats, fp16)
  k_gemm16<false><<<NN / 128, 256, 0, stream>>>(B1, Wt2, dinv, A1, 128);
  k_agg2ro<<<NN / 4, 256, 0, stream>>>((const __half2*)A1, bounds, csr, dinv, c2b, rw, rb, o8h);

  // fc1 as MFMA (no atomics, plain-store K-partials)
  {
    dim3 g(25, 4);
    k_fc1m<<<g, 256, 0, stream>>>(o8h, Wtf, zp);
  }
  k_bn<<<400, 128, 0, stream>>>(zp, bng, bnb, gs, gb);
  k_fc2<<<128, 256, 0, stream>>>(zp, gs, gb, f2w, f2b, out);
}